// Round 1
// baseline (914.608 us; speedup 1.0000x reference)
//
#include <hip/hip_runtime.h>
#include <cstdint>
#include <cstddef>

// Problem shape (fixed by setup_inputs): B=4, T=4096, E=1024
#define B_ 4
#define T_ 4096
#define E_ 1024
#define BT_ (B_*T_)

typedef unsigned short u16;
typedef unsigned int   u32;
typedef __attribute__((ext_vector_type(8))) short bf8;   // 8 x bf16 (4 VGPRs)
typedef __attribute__((ext_vector_type(4))) float f4;

__device__ inline u16 f2bf(float f){            // RNE float->bf16
  u32 x = __float_as_uint(f);
  u32 r = (x + 0x7fffu + ((x >> 16) & 1u)) >> 16;
  return (u16)r;
}
__device__ inline float bf2f(u32 u){ return __uint_as_float(u << 16); }

__device__ inline float wredsum(float v){
  #pragma unroll
  for (int o = 32; o; o >>= 1) v += __shfl_xor(v, o, 64);
  return v;
}

// ---- K1: key/query scalars (one wave per token row) -----------------------
__global__ __launch_bounds__(256) void k_prep(const float* __restrict__ token,
    const float* __restrict__ Wk, const float* __restrict__ bk,
    const float* __restrict__ Wq, const float* __restrict__ bq,
    float* __restrict__ key, float* __restrict__ query){
  int row  = blockIdx.x * 4 + (threadIdx.x >> 6);
  int lane = threadIdx.x & 63;
  const f4* tr = (const f4*)(token + (size_t)row * E_);
  const f4* wk = (const f4*)Wk;
  const f4* wq = (const f4*)Wq;
  float sk = 0.f, sq = 0.f;
  #pragma unroll
  for (int it = 0; it < 4; ++it){
    f4 t = tr[lane + 64*it];
    f4 a = wk[lane + 64*it];
    f4 b = wq[lane + 64*it];
    sk += t.x*a.x + t.y*a.y + t.z*a.z + t.w*a.w;
    sq += t.x*b.x + t.y*b.y + t.z*b.z + t.w*b.w;
  }
  sk = wredsum(sk); sq = wredsum(sq);
  if (lane == 0){ key[row] = sk + bk[0]; query[row] = sq + bq[0]; }
}

// ---- K2: per-batch kmax/kmin ----------------------------------------------
__global__ __launch_bounds__(256) void k_stats(const float* __restrict__ key,
                                               float* __restrict__ kstat){
  int b = blockIdx.x;
  float mx = -3.4e38f, mn = 3.4e38f;
  for (int i = threadIdx.x; i < T_; i += 256){
    float v = key[b*T_ + i];
    mx = fmaxf(mx, v); mn = fminf(mn, v);
  }
  #pragma unroll
  for (int o = 32; o; o >>= 1){
    mx = fmaxf(mx, __shfl_xor(mx, o, 64));
    mn = fminf(mn, __shfl_xor(mn, o, 64));
  }
  __shared__ float smx[4], smn[4];
  int w = threadIdx.x >> 6;
  if ((threadIdx.x & 63) == 0){ smx[w] = mx; smn[w] = mn; }
  __syncthreads();
  if (threadIdx.x == 0){
    mx = fmaxf(fmaxf(smx[0], smx[1]), fmaxf(smx[2], smx[3]));
    mn = fminf(fminf(smn[0], smn[1]), fminf(smn[2], smn[3]));
    kstat[b*2] = mx; kstat[b*2+1] = mn;
  }
}

// ---- K3: softmax row max (analytic) + denominator (one wave per row) -------
__global__ __launch_bounds__(256) void k_denom(const float* __restrict__ key,
    const float* __restrict__ query, const float* __restrict__ kstat,
    float* __restrict__ mrow, float* __restrict__ drow){
  int row  = blockIdx.x * 4 + (threadIdx.x >> 6);
  int lane = threadIdx.x & 63;
  int b = row / T_;
  float q = query[row];
  float m = (q > 0.f) ? q * kstat[b*2] : q * kstat[b*2+1];
  const float* kb = key + (size_t)b * T_;
  float s = 0.f;
  for (int x = lane; x < T_; x += 64) s += __expf(q * kb[x] - m);
  s = wredsum(s);
  if (lane == 0){ mrow[row] = m; drow[row] = s; }
}

// ---- K4: Wv (fp32 [k][n]) -> WvT (bf16 [n][k]) -----------------------------
__global__ __launch_bounds__(256) void k_wvT(const float* __restrict__ Wv,
                                             u16* __restrict__ wvT){
  __shared__ u16 tile[32][33];
  int nt = blockIdx.x, kt = blockIdx.y;
  int tx = threadIdx.x & 31, ty0 = threadIdx.x >> 5;
  #pragma unroll
  for (int p = 0; p < 4; ++p){
    int ty = ty0 + p*8;
    tile[ty][tx] = f2bf(Wv[(size_t)(kt*32+ty)*E_ + nt*32 + tx]);
  }
  __syncthreads();
  #pragma unroll
  for (int p = 0; p < 4; ++p){
    int ty = ty0 + p*8;
    wvT[(size_t)(nt*32+ty)*E_ + kt*32 + tx] = tile[tx][ty];
  }
}

// ---- GEMM: C[64x64] tile, 4 waves (2x2 of 32x32), K-step 32 ----------------
// MODE 0: A = fp32 token, out = bf16(acc + bias)            (value GEMM)
// MODE 1: A = bf16 z1,    out = bf16(acc + bias + resid)    (gemm2 + residual)
template<int MODE>
__global__ __launch_bounds__(256) void k_gemm(const void* __restrict__ Ap,
    const u16* __restrict__ Bt /* [N][K] bf16 */, const float* __restrict__ bias,
    const u16* __restrict__ resid, u16* __restrict__ outp){
  __shared__ __align__(16) u16 lds_a[64*40];   // 64 rows x 32 k, stride 40 (pad)
  const int K = E_, N = E_;
  int m0 = blockIdx.x * 64, n0 = blockIdx.y * 64;
  int tid = threadIdx.x, lane = tid & 63, w = tid >> 6;
  int wr = w >> 1, wc = w & 1, h = lane >> 4, l15 = lane & 15;
  int ar = tid >> 2, as = tid & 3;
  f4 acc[2][2] = {};
  const u16* bbase = Bt + (size_t)(n0 + wc*32 + l15) * K + h*8;
  for (int k0 = 0; k0 < K; k0 += 32){
    bf8 pk;
    if (MODE == 0){
      const float* A = (const float*)Ap;
      const float* ap = A + (size_t)(m0 + ar) * K + k0 + as*8;
      f4 v0 = *(const f4*)ap;
      f4 v1 = *(const f4*)(ap + 4);
      pk[0]=(short)f2bf(v0.x); pk[1]=(short)f2bf(v0.y);
      pk[2]=(short)f2bf(v0.z); pk[3]=(short)f2bf(v0.w);
      pk[4]=(short)f2bf(v1.x); pk[5]=(short)f2bf(v1.y);
      pk[6]=(short)f2bf(v1.z); pk[7]=(short)f2bf(v1.w);
    } else {
      const u16* A = (const u16*)Ap;
      pk = *(const bf8*)(A + (size_t)(m0 + ar) * K + k0 + as*8);
    }
    __syncthreads();                       // previous iter's reads done
    *(bf8*)&lds_a[ar*40 + as*8] = pk;
    __syncthreads();
    bf8 a0 = *(const bf8*)&lds_a[(wr*32 +      l15)*40 + h*8];
    bf8 a1 = *(const bf8*)&lds_a[(wr*32 + 16 + l15)*40 + h*8];
    bf8 b0 = *(const bf8*)(bbase + k0);
    bf8 b1 = *(const bf8*)(bbase + (size_t)16*K + k0);
    acc[0][0] = __builtin_amdgcn_mfma_f32_16x16x32_bf16(a0, b0, acc[0][0], 0,0,0);
    acc[0][1] = __builtin_amdgcn_mfma_f32_16x16x32_bf16(a0, b1, acc[0][1], 0,0,0);
    acc[1][0] = __builtin_amdgcn_mfma_f32_16x16x32_bf16(a1, b0, acc[1][0], 0,0,0);
    acc[1][1] = __builtin_amdgcn_mfma_f32_16x16x32_bf16(a1, b1, acc[1][1], 0,0,0);
  }
  #pragma unroll
  for (int fm = 0; fm < 2; ++fm)
  #pragma unroll
  for (int fn = 0; fn < 2; ++fn)
  #pragma unroll
  for (int r = 0; r < 4; ++r){
    int row = m0 + wr*32 + fm*16 + h*4 + r;     // C/D: row=(lane>>4)*4+reg
    int col = n0 + wc*32 + fn*16 + l15;         //      col=lane&15
    float v = acc[fm][fn][r] + bias[col];
    if (MODE == 1) v += bf2f(resid[(size_t)row * N + col]);
    outp[(size_t)row * N + col] = f2bf(v);
  }
}

// ---- K6: value [b][t][e] -> valT [b][e][t] (bf16, 32x32 LDS tiles) ---------
__global__ __launch_bounds__(256) void k_transpose(const u16* __restrict__ in,
                                                   u16* __restrict__ out){
  __shared__ u16 tile[32][33];
  int b = blockIdx.z, xt = blockIdx.x, et = blockIdx.y;
  int tx = threadIdx.x & 31, ty0 = threadIdx.x >> 5;
  const u16* ib = in  + (size_t)b * T_ * E_;
  u16*       ob = out + (size_t)b * E_ * T_;
  #pragma unroll
  for (int p = 0; p < 4; ++p){
    int ty = ty0 + p*8;
    tile[ty][tx] = ib[(size_t)(xt*32+ty)*E_ + et*32 + tx];
  }
  __syncthreads();
  #pragma unroll
  for (int p = 0; p < 4; ++p){
    int ty = ty0 + p*8;
    ob[(size_t)(et*32+ty)*T_ + xt*32 + tx] = tile[tx][ty];
  }
}

// ---- K7: PV — z[t][e] = (P @ V)/d;  P generated on the fly ------------------
// Block tile 64(t) x 128(e); 4 waves (2x2), each 32t x 64e; K-step 32 over x.
__global__ __launch_bounds__(256) void k_pv(const float* __restrict__ query,
    const float* __restrict__ key, const float* __restrict__ mrow,
    const float* __restrict__ drow, const u16* __restrict__ valT,
    u16* __restrict__ zraw){
  __shared__ __align__(16) u16 lds_p[64*40];
  int b  = blockIdx.z;
  int t0 = blockIdx.x * 64, e0 = blockIdx.y * 128;
  int tid = threadIdx.x, lane = tid & 63, w = tid >> 6;
  int wr = w >> 1, wc = w & 1, h = lane >> 4, l15 = lane & 15;
  int pr = tid >> 2, ps = tid & 3;
  float qv = query[b*T_ + t0 + pr];
  float mv = mrow [b*T_ + t0 + pr];
  const float* kb = key + (size_t)b * T_;
  const u16*   vb = valT + (size_t)b * E_ * T_
                         + (size_t)(e0 + wc*64 + l15) * T_ + h*8;
  f4 acc[2][4] = {};
  for (int x0 = 0; x0 < T_; x0 += 32){
    const float* kp = kb + x0 + ps*8;
    f4 k0v = *(const f4*)kp;
    f4 k1v = *(const f4*)(kp + 4);
    bf8 pk;
    pk[0]=(short)f2bf(__expf(qv*k0v.x - mv));
    pk[1]=(short)f2bf(__expf(qv*k0v.y - mv));
    pk[2]=(short)f2bf(__expf(qv*k0v.z - mv));
    pk[3]=(short)f2bf(__expf(qv*k0v.w - mv));
    pk[4]=(short)f2bf(__expf(qv*k1v.x - mv));
    pk[5]=(short)f2bf(__expf(qv*k1v.y - mv));
    pk[6]=(short)f2bf(__expf(qv*k1v.z - mv));
    pk[7]=(short)f2bf(__expf(qv*k1v.w - mv));
    __syncthreads();
    *(bf8*)&lds_p[pr*40 + ps*8] = pk;
    __syncthreads();
    bf8 a0 = *(const bf8*)&lds_p[(wr*32 +      l15)*40 + h*8];
    bf8 a1 = *(const bf8*)&lds_p[(wr*32 + 16 + l15)*40 + h*8];
    #pragma unroll
    for (int fn = 0; fn < 4; ++fn){
      bf8 bfr = *(const bf8*)(vb + (size_t)fn*16*T_ + x0);
      acc[0][fn] = __builtin_amdgcn_mfma_f32_16x16x32_bf16(a0, bfr, acc[0][fn], 0,0,0);
      acc[1][fn] = __builtin_amdgcn_mfma_f32_16x16x32_bf16(a1, bfr, acc[1][fn], 0,0,0);
    }
  }
  #pragma unroll
  for (int fm = 0; fm < 2; ++fm){
    #pragma unroll
    for (int r = 0; r < 4; ++r){
      int row = t0 + wr*32 + fm*16 + h*4 + r;
      float inv = 1.f / drow[b*T_ + row];
      #pragma unroll
      for (int fn = 0; fn < 4; ++fn){
        int col = e0 + wc*64 + fn*16 + l15;
        zraw[((size_t)b*T_ + row)*E_ + col] = f2bf(acc[fm][fn][r] * inv);
      }
    }
  }
}

// ---- LN (one wave per row). FINAL=0: bf16 out. FINAL=1: relu -> fp32 out ---
template<int FINAL>
__global__ __launch_bounds__(256) void k_ln(const u16* __restrict__ in,
    const float* __restrict__ g, const float* __restrict__ bt,
    void* __restrict__ outp){
  int row  = blockIdx.x * 4 + (threadIdx.x >> 6);
  int lane = threadIdx.x & 63;
  const u16* r = in + (size_t)row * E_;
  uint4 u0 = *(const uint4*)(r + lane*16);
  uint4 u1 = *(const uint4*)(r + lane*16 + 8);
  u32 uu[8] = {u0.x, u0.y, u0.z, u0.w, u1.x, u1.y, u1.z, u1.w};
  float v[16];
  #pragma unroll
  for (int j = 0; j < 8; ++j){
    v[2*j]   = bf2f(uu[j] & 0xffffu);
    v[2*j+1] = bf2f(uu[j] >> 16);
  }
  float s1 = 0.f, s2 = 0.f;
  #pragma unroll
  for (int j = 0; j < 16; ++j){ s1 += v[j]; s2 += v[j]*v[j]; }
  s1 = wredsum(s1); s2 = wredsum(s2);
  float mean = s1 * (1.f/E_);
  float var  = s2 * (1.f/E_) - mean*mean;
  float rs   = rsqrtf(var + 1e-3f);
  const f4* g4 = (const f4*)g + lane*4;
  const f4* b4 = (const f4*)bt + lane*4;
  float o[16];
  #pragma unroll
  for (int jj = 0; jj < 4; ++jj){
    f4 gg = g4[jj], bb = b4[jj];
    o[4*jj+0] = (v[4*jj+0]-mean)*rs*gg.x + bb.x;
    o[4*jj+1] = (v[4*jj+1]-mean)*rs*gg.y + bb.y;
    o[4*jj+2] = (v[4*jj+2]-mean)*rs*gg.z + bb.z;
    o[4*jj+3] = (v[4*jj+3]-mean)*rs*gg.w + bb.w;
  }
  if (FINAL){
    f4* od = (f4*)((float*)outp + (size_t)row * E_ + lane*16);
    #pragma unroll
    for (int jj = 0; jj < 4; ++jj){
      f4 t;
      t.x = fmaxf(o[4*jj+0], 0.f); t.y = fmaxf(o[4*jj+1], 0.f);
      t.z = fmaxf(o[4*jj+2], 0.f); t.w = fmaxf(o[4*jj+3], 0.f);
      od[jj] = t;
    }
  } else {
    u16* ob = (u16*)outp + (size_t)row * E_ + lane*16;
    u32 pu[8];
    #pragma unroll
    for (int j = 0; j < 8; ++j)
      pu[j] = (u32)f2bf(o[2*j]) | ((u32)f2bf(o[2*j+1]) << 16);
    uint4 w0 = {pu[0], pu[1], pu[2], pu[3]};
    uint4 w1 = {pu[4], pu[5], pu[6], pu[7]};
    *(uint4*)ob       = w0;
    *(uint4*)(ob + 8) = w1;
  }
}

// ---------------------------------------------------------------------------
extern "C" void kernel_launch(void* const* d_in, const int* in_sizes, int n_in,
                              void* d_out, int out_size, void* d_ws, size_t ws_size,
                              hipStream_t stream){
  const float* token = (const float*)d_in[0];
  const float* Wk    = (const float*)d_in[1];
  const float* bk    = (const float*)d_in[2];
  const float* Wq    = (const float*)d_in[3];
  const float* bq    = (const float*)d_in[4];
  const float* Wv    = (const float*)d_in[5];
  const float* bv    = (const float*)d_in[6];
  const float* g1    = (const float*)d_in[7];
  const float* b1    = (const float*)d_in[8];
  const float* g2    = (const float*)d_in[9];
  const float* b2    = (const float*)d_in[10];

  // Workspace layout (needs 68 MiB):
  //   [0, 2MiB)        WvT bf16 [N][K]
  //   [2MiB, +64KiB*4) key / query / mrow / drow   (+ kstat)
  //   S0 @ 4MiB  (32 MiB): value bf16 -> zraw bf16 -> y bf16
  //   S1 @ 36MiB (32 MiB): valT bf16  -> z1 bf16
  char* ws = (char*)d_ws;
  u16*   wvT   = (u16*)ws;
  float* key   = (float*)(ws + (2u<<20));
  float* query = (float*)(ws + (2u<<20) + (64u<<10));
  float* mrow  = (float*)(ws + (2u<<20) + (128u<<10));
  float* drow  = (float*)(ws + (2u<<20) + (192u<<10));
  float* kstat = (float*)(ws + (2u<<20) + (256u<<10));
  u16* S0 = (u16*)(ws + (4u<<20));
  u16* S1 = (u16*)(ws + (36u<<20));
  float* out = (float*)d_out;

  k_prep <<<dim3(BT_/4), 256, 0, stream>>>(token, Wk, bk, Wq, bq, key, query);
  k_stats<<<dim3(B_),    256, 0, stream>>>(key, kstat);
  k_denom<<<dim3(BT_/4), 256, 0, stream>>>(key, query, kstat, mrow, drow);
  k_wvT  <<<dim3(E_/32, E_/32), 256, 0, stream>>>(Wv, wvT);
  k_gemm<0><<<dim3(BT_/64, E_/64), 256, 0, stream>>>(token, wvT, bv, nullptr, S0);
  k_transpose<<<dim3(T_/32, E_/32, B_), 256, 0, stream>>>(S0, S1);
  k_pv   <<<dim3(T_/64, E_/128, B_), 256, 0, stream>>>(query, key, mrow, drow, S1, S0);
  k_ln<0><<<dim3(BT_/4), 256, 0, stream>>>(S0, g1, b1, (void*)S1);
  k_gemm<1><<<dim3(BT_/64, E_/64), 256, 0, stream>>>(S1, wvT, bv, S1, S0);
  k_ln<1><<<dim3(BT_/4), 256, 0, stream>>>(S0, g2, b2, (void*)out);
}

// Round 2
// 674.037 us; speedup vs baseline: 1.3569x; 1.3569x over previous
//
#include <hip/hip_runtime.h>
#include <cstdint>
#include <cstddef>

// Problem shape (fixed by setup_inputs): B=4, T=4096, E=1024
#define B_ 4
#define T_ 4096
#define E_ 1024
#define BT_ (B_*T_)

typedef unsigned short u16;
typedef unsigned int   u32;
typedef __attribute__((ext_vector_type(8))) short bf8;   // 8 x bf16 (4 VGPRs)
typedef __attribute__((ext_vector_type(4))) float f4;

__device__ inline u16 f2bf(float f){            // RNE float->bf16
  u32 x = __float_as_uint(f);
  u32 r = (x + 0x7fffu + ((x >> 16) & 1u)) >> 16;
  return (u16)r;
}
__device__ inline float bf2f(u32 u){ return __uint_as_float(u << 16); }

__device__ inline float wredsum(float v){
  #pragma unroll
  for (int o = 32; o; o >>= 1) v += __shfl_xor(v, o, 64);
  return v;
}

// async global->LDS, 16B per lane; LDS dest is wave-uniform base + lane*16
__device__ inline void gld_lds16(const void* g, void* l){
  __builtin_amdgcn_global_load_lds(
      (const __attribute__((address_space(1))) void*)g,
      (__attribute__((address_space(3))) void*)l, 16, 0, 0);
}

#define LOG2E_ 1.44269504088896340f

// ---- K1: key/query scalars + bf16 token copy (one wave per row) ------------
__global__ __launch_bounds__(256) void k_prep(const float* __restrict__ token,
    const float* __restrict__ Wk, const float* __restrict__ bk,
    const float* __restrict__ Wq, const float* __restrict__ bq,
    float* __restrict__ key, float* __restrict__ query, u16* __restrict__ tokbf){
  int row  = blockIdx.x * 4 + (threadIdx.x >> 6);
  int lane = threadIdx.x & 63;
  const f4* tr = (const f4*)(token + (size_t)row * E_);
  const f4* wk = (const f4*)Wk;
  const f4* wq = (const f4*)Wq;
  float sk = 0.f, sq = 0.f;
  #pragma unroll
  for (int it = 0; it < 4; ++it){
    f4 t = tr[lane + 64*it];
    f4 a = wk[lane + 64*it];
    f4 b = wq[lane + 64*it];
    sk += t.x*a.x + t.y*a.y + t.z*a.z + t.w*a.w;
    sq += t.x*b.x + t.y*b.y + t.z*b.z + t.w*b.w;
    u32 lo = (u32)f2bf(t.x) | ((u32)f2bf(t.y) << 16);
    u32 hi = (u32)f2bf(t.z) | ((u32)f2bf(t.w) << 16);
    uint2 pk; pk.x = lo; pk.y = hi;
    *(uint2*)(tokbf + (size_t)row * E_ + (lane + 64*it)*4) = pk;
  }
  sk = wredsum(sk); sq = wredsum(sq);
  if (lane == 0){ key[row] = sk + bk[0]; query[row] = sq + bq[0]; }
}

// ---- K2: per-batch kmax/kmin ----------------------------------------------
__global__ __launch_bounds__(256) void k_stats(const float* __restrict__ key,
                                               float* __restrict__ kstat){
  int b = blockIdx.x;
  float mx = -3.4e38f, mn = 3.4e38f;
  for (int i = threadIdx.x; i < T_; i += 256){
    float v = key[b*T_ + i];
    mx = fmaxf(mx, v); mn = fminf(mn, v);
  }
  #pragma unroll
  for (int o = 32; o; o >>= 1){
    mx = fmaxf(mx, __shfl_xor(mx, o, 64));
    mn = fminf(mn, __shfl_xor(mn, o, 64));
  }
  __shared__ float smx[4], smn[4];
  int w = threadIdx.x >> 6;
  if ((threadIdx.x & 63) == 0){ smx[w] = mx; smn[w] = mn; }
  __syncthreads();
  if (threadIdx.x == 0){
    mx = fmaxf(fmaxf(smx[0], smx[1]), fmaxf(smx[2], smx[3]));
    mn = fminf(fminf(smn[0], smn[1]), fminf(smn[2], smn[3]));
    kstat[b*2] = mx; kstat[b*2+1] = mn;
  }
}

// ---- K3: softmax row max (analytic) + denominator (one wave per row) -------
__global__ __launch_bounds__(256) void k_denom(const float* __restrict__ key,
    const float* __restrict__ query, const float* __restrict__ kstat,
    float* __restrict__ mrow, float* __restrict__ drow){
  int row  = blockIdx.x * 4 + (threadIdx.x >> 6);
  int lane = threadIdx.x & 63;
  int b = row / T_;
  float q = query[row];
  float m = (q > 0.f) ? q * kstat[b*2] : q * kstat[b*2+1];
  float qL = q * LOG2E_, mL = m * LOG2E_;
  const float* kb = key + (size_t)b * T_;
  float s = 0.f;
  for (int x = lane; x < T_; x += 64) s += exp2f(qL * kb[x] - mL);
  s = wredsum(s);
  if (lane == 0){ mrow[row] = m; drow[row] = s; }
}

// ---- K4: Wv (fp32 [k][n]) -> WvT (bf16 [n][k]) -----------------------------
__global__ __launch_bounds__(256) void k_wvT(const float* __restrict__ Wv,
                                             u16* __restrict__ wvT){
  __shared__ u16 tile[32][33];
  int nt = blockIdx.x, kt = blockIdx.y;
  int tx = threadIdx.x & 31, ty0 = threadIdx.x >> 5;
  #pragma unroll
  for (int p = 0; p < 4; ++p){
    int ty = ty0 + p*8;
    tile[ty][tx] = f2bf(Wv[(size_t)(kt*32+ty)*E_ + nt*32 + tx]);
  }
  __syncthreads();
  #pragma unroll
  for (int p = 0; p < 4; ++p){
    int ty = ty0 + p*8;
    wvT[(size_t)(nt*32+ty)*E_ + kt*32 + tx] = tile[tx][ty];
  }
}

// ---- GEMM: 128x128 tile, 4 waves (2x2, wave tile 64x64), BK=32 -------------
// A [M][K] bf16, Bt [N][K] bf16. Staged via global_load_lds(16B) into linear
// LDS with XOR slot swizzle (slot ^= (row>>1)&3) applied on the GLOBAL source
// and on the ds_read address (both-sides swizzle -> 2-way banks = free).
// MODE 0: out = valT[b][e][t] = bf16(acc + bias)   (value GEMM, transposed)
// MODE 1: out[row][col] = bf16(acc + bias + resid) (gemm2 + residual)
template<int MODE>
__global__ __launch_bounds__(256) void k_gemm(const u16* __restrict__ A,
    const u16* __restrict__ Bt, const float* __restrict__ bias,
    const u16* __restrict__ resid, u16* __restrict__ outp){
  __shared__ __align__(16) u16 lA[128*32];
  __shared__ __align__(16) u16 lB[128*32];
  const int K = E_, N = E_;
  // XCD swizzle: 1024 blocks; blocks sharing the same m-panel land on one XCD
  int bid = blockIdx.x;
  int xcd = bid & 7, rr = bid >> 3;
  int m0 = (xcd + (rr >> 3)*8) * 128;
  int n0 = (rr & 7) * 128;
  int tid = threadIdx.x, lane = tid & 63, w = tid >> 6;
  int wr = w >> 1, wc = w & 1, h = lane >> 4, l15 = lane & 15;
  f4 acc[4][4] = {};
  for (int k0 = 0; k0 < K; k0 += 32){
    __syncthreads();                       // previous iter's reads done
    #pragma unroll
    for (int p = 0; p < 2; ++p){
      int u = p*256 + w*64 + lane;
      int row = u >> 2;
      int sl  = (u & 3) ^ ((row >> 1) & 3);
      const u16* ga = A  + (size_t)(m0 + row) * K + k0 + sl*8;
      const u16* gb = Bt + (size_t)(n0 + row) * K + k0 + sl*8;
      gld_lds16(ga, lA + (size_t)(p*256 + w*64)*8);
      gld_lds16(gb, lB + (size_t)(p*256 + w*64)*8);
    }
    __syncthreads();                       // staging complete (vmcnt drained)
    bf8 a[4], bfr[4];
    #pragma unroll
    for (int f = 0; f < 4; ++f){
      int ra = wr*64 + f*16 + l15;
      int rb = wc*64 + f*16 + l15;
      a[f]   = *(const bf8*)&lA[ra*32 + ((h ^ ((ra >> 1) & 3)) & 3)*8];
      bfr[f] = *(const bf8*)&lB[rb*32 + ((h ^ ((rb >> 1) & 3)) & 3)*8];
    }
    #pragma unroll
    for (int fm = 0; fm < 4; ++fm)
    #pragma unroll
    for (int fn = 0; fn < 4; ++fn)
      acc[fm][fn] = __builtin_amdgcn_mfma_f32_16x16x32_bf16(a[fm], bfr[fn], acc[fm][fn], 0,0,0);
  }
  if (MODE == 0){
    // transposed write: valT[b][e][t]; each lane holds 4 consecutive t at fixed e
    #pragma unroll
    for (int fm = 0; fm < 4; ++fm){
      int rowg = m0 + wr*64 + fm*16 + h*4;          // global token index
      int bb = rowg >> 12;                          // T_=4096
      int tt = rowg & (T_-1);
      #pragma unroll
      for (int fn = 0; fn < 4; ++fn){
        int col = n0 + wc*64 + fn*16 + l15;         // e
        float bv = bias[col];
        u16 q0 = f2bf(acc[fm][fn][0] + bv);
        u16 q1 = f2bf(acc[fm][fn][1] + bv);
        u16 q2 = f2bf(acc[fm][fn][2] + bv);
        u16 q3 = f2bf(acc[fm][fn][3] + bv);
        uint2 pk; pk.x = (u32)q0 | ((u32)q1 << 16); pk.y = (u32)q2 | ((u32)q3 << 16);
        *(uint2*)(outp + ((size_t)bb*E_ + col)*T_ + tt) = pk;
      }
    }
  } else {
    #pragma unroll
    for (int fm = 0; fm < 4; ++fm)
    #pragma unroll
    for (int fn = 0; fn < 4; ++fn)
    #pragma unroll
    for (int r = 0; r < 4; ++r){
      int row = m0 + wr*64 + fm*16 + h*4 + r;
      int col = n0 + wc*64 + fn*16 + l15;
      float v = acc[fm][fn][r] + bias[col] + bf2f(resid[(size_t)row * N + col]);
      outp[(size_t)row * N + col] = f2bf(v);
    }
  }
}

// ---- K7: PV — z[t][e] = (P @ V)/d;  P generated cooperatively in LDS -------
// 512 threads = 8 waves (2 t x 4 e). Block tile 64(t) x 512(e), K-step 32.
// Double-buffered LDS P -> single barrier per K-step. XCD panel swizzle:
// panel = (e-half, batch) -> 8 panels == 8 XCDs, each valT panel (4MiB) stays
// L2-resident on its XCD.
__global__ __launch_bounds__(512) void k_pv(const float* __restrict__ query,
    const float* __restrict__ key, const float* __restrict__ mrow,
    const float* __restrict__ drow, const u16* __restrict__ valT,
    u16* __restrict__ zraw){
  __shared__ __align__(16) u16 lds_p[2][64*40];
  int bid = blockIdx.x;                 // 512 blocks
  int panel = bid & 7;                  // -> XCD
  int b  = panel >> 1;
  int e0 = (panel & 1) * 512;
  int t0 = (bid >> 3) * 64;
  int tid = threadIdx.x, lane = tid & 63, w = tid >> 6;
  int wr = w >> 2, wc = w & 3, h = lane >> 4, l15 = lane & 15;
  int pr = tid >> 3, ps = tid & 7;
  float qv = query[b*T_ + t0 + pr] * LOG2E_;
  float mv = mrow [b*T_ + t0 + pr] * LOG2E_;
  const float* kb = key + (size_t)b * T_;
  const u16*   vb = valT + (size_t)b * E_ * T_
                         + (size_t)(e0 + wc*128 + l15) * T_ + h*8;
  f4 acc[2][8] = {};
  { // prologue: generate P(x0=0) into buf 0
    f4 kv = *(const f4*)(kb + ps*4);
    u16 p0 = f2bf(exp2f(qv*kv.x - mv));
    u16 p1 = f2bf(exp2f(qv*kv.y - mv));
    u16 p2 = f2bf(exp2f(qv*kv.z - mv));
    u16 p3 = f2bf(exp2f(qv*kv.w - mv));
    uint2 pk; pk.x = (u32)p0 | ((u32)p1<<16); pk.y = (u32)p2 | ((u32)p3<<16);
    *(uint2*)&lds_p[0][pr*40 + ps*4] = pk;
  }
  __syncthreads();
  int cur = 0;
  for (int x0 = 0; x0 < T_; x0 += 32){
    if (x0 + 32 < T_){                  // generate next P into buf^1
      f4 kv = *(const f4*)(kb + x0 + 32 + ps*4);
      u16 p0 = f2bf(exp2f(qv*kv.x - mv));
      u16 p1 = f2bf(exp2f(qv*kv.y - mv));
      u16 p2 = f2bf(exp2f(qv*kv.z - mv));
      u16 p3 = f2bf(exp2f(qv*kv.w - mv));
      uint2 pk; pk.x = (u32)p0 | ((u32)p1<<16); pk.y = (u32)p2 | ((u32)p3<<16);
      *(uint2*)&lds_p[cur^1][pr*40 + ps*4] = pk;
    }
    bf8 a0 = *(const bf8*)&lds_p[cur][(wr*32 +      l15)*40 + h*8];
    bf8 a1 = *(const bf8*)&lds_p[cur][(wr*32 + 16 + l15)*40 + h*8];
    #pragma unroll
    for (int fn = 0; fn < 8; ++fn){
      bf8 bv = *(const bf8*)(vb + (size_t)fn*16*T_ + x0);
      acc[0][fn] = __builtin_amdgcn_mfma_f32_16x16x32_bf16(a0, bv, acc[0][fn], 0,0,0);
      acc[1][fn] = __builtin_amdgcn_mfma_f32_16x16x32_bf16(a1, bv, acc[1][fn], 0,0,0);
    }
    __syncthreads();
    cur ^= 1;
  }
  #pragma unroll
  for (int fm = 0; fm < 2; ++fm){
    #pragma unroll
    for (int r = 0; r < 4; ++r){
      int row = t0 + wr*32 + fm*16 + h*4 + r;
      float inv = 1.f / drow[b*T_ + row];
      #pragma unroll
      for (int fn = 0; fn < 8; ++fn){
        int col = e0 + wc*128 + fn*16 + l15;
        zraw[((size_t)b*T_ + row)*E_ + col] = f2bf(acc[fm][fn][r] * inv);
      }
    }
  }
}

// ---- LN (one wave per row). FINAL=0: bf16 out. FINAL=1: relu -> fp32 out ---
template<int FINAL>
__global__ __launch_bounds__(256) void k_ln(const u16* __restrict__ in,
    const float* __restrict__ g, const float* __restrict__ bt,
    void* __restrict__ outp){
  int row  = blockIdx.x * 4 + (threadIdx.x >> 6);
  int lane = threadIdx.x & 63;
  const u16* r = in + (size_t)row * E_;
  uint4 u0 = *(const uint4*)(r + lane*16);
  uint4 u1 = *(const uint4*)(r + lane*16 + 8);
  u32 uu[8] = {u0.x, u0.y, u0.z, u0.w, u1.x, u1.y, u1.z, u1.w};
  float v[16];
  #pragma unroll
  for (int j = 0; j < 8; ++j){
    v[2*j]   = bf2f(uu[j] & 0xffffu);
    v[2*j+1] = bf2f(uu[j] >> 16);
  }
  float s1 = 0.f, s2 = 0.f;
  #pragma unroll
  for (int j = 0; j < 16; ++j){ s1 += v[j]; s2 += v[j]*v[j]; }
  s1 = wredsum(s1); s2 = wredsum(s2);
  float mean = s1 * (1.f/E_);
  float var  = s2 * (1.f/E_) - mean*mean;
  float rs   = rsqrtf(var + 1e-3f);
  const f4* g4 = (const f4*)g + lane*4;
  const f4* b4 = (const f4*)bt + lane*4;
  float o[16];
  #pragma unroll
  for (int jj = 0; jj < 4; ++jj){
    f4 gg = g4[jj], bb = b4[jj];
    o[4*jj+0] = (v[4*jj+0]-mean)*rs*gg.x + bb.x;
    o[4*jj+1] = (v[4*jj+1]-mean)*rs*gg.y + bb.y;
    o[4*jj+2] = (v[4*jj+2]-mean)*rs*gg.z + bb.z;
    o[4*jj+3] = (v[4*jj+3]-mean)*rs*gg.w + bb.w;
  }
  if (FINAL){
    f4* od = (f4*)((float*)outp + (size_t)row * E_ + lane*16);
    #pragma unroll
    for (int jj = 0; jj < 4; ++jj){
      f4 t;
      t.x = fmaxf(o[4*jj+0], 0.f); t.y = fmaxf(o[4*jj+1], 0.f);
      t.z = fmaxf(o[4*jj+2], 0.f); t.w = fmaxf(o[4*jj+3], 0.f);
      od[jj] = t;
    }
  } else {
    u16* ob = (u16*)outp + (size_t)row * E_ + lane*16;
    u32 pu[8];
    #pragma unroll
    for (int j = 0; j < 8; ++j)
      pu[j] = (u32)f2bf(o[2*j]) | ((u32)f2bf(o[2*j+1]) << 16);
    uint4 w0 = {pu[0], pu[1], pu[2], pu[3]};
    uint4 w1 = {pu[4], pu[5], pu[6], pu[7]};
    *(uint4*)ob       = w0;
    *(uint4*)(ob + 8) = w1;
  }
}

// ---------------------------------------------------------------------------
extern "C" void kernel_launch(void* const* d_in, const int* in_sizes, int n_in,
                              void* d_out, int out_size, void* d_ws, size_t ws_size,
                              hipStream_t stream){
  const float* token = (const float*)d_in[0];
  const float* Wk    = (const float*)d_in[1];
  const float* bk    = (const float*)d_in[2];
  const float* Wq    = (const float*)d_in[3];
  const float* bq    = (const float*)d_in[4];
  const float* Wv    = (const float*)d_in[5];
  const float* bv    = (const float*)d_in[6];
  const float* g1    = (const float*)d_in[7];
  const float* b1    = (const float*)d_in[8];
  const float* g2    = (const float*)d_in[9];
  const float* b2    = (const float*)d_in[10];

  // Workspace layout (68 MiB):
  //   [0, 2MiB)   WvT bf16 [N][K]
  //   [2MiB, ..)  key / query / mrow / drow / kstat
  //   X @ 4MiB  (32 MiB): token_bf16 -> zraw bf16 -> y bf16
  //   V @ 36MiB (32 MiB): valT bf16 [b][e][t] -> z1 bf16
  char* ws = (char*)d_ws;
  u16*   wvT   = (u16*)ws;
  float* key   = (float*)(ws + (2u<<20));
  float* query = (float*)(ws + (2u<<20) + (64u<<10));
  float* mrow  = (float*)(ws + (2u<<20) + (128u<<10));
  float* drow  = (float*)(ws + (2u<<20) + (192u<<10));
  float* kstat = (float*)(ws + (2u<<20) + (256u<<10));
  u16* X = (u16*)(ws + (4u<<20));
  u16* V = (u16*)(ws + (36u<<20));
  float* out = (float*)d_out;

  k_prep <<<dim3(BT_/4), 256, 0, stream>>>(token, Wk, bk, Wq, bq, key, query, X);
  k_stats<<<dim3(B_),    256, 0, stream>>>(key, kstat);
  k_denom<<<dim3(BT_/4), 256, 0, stream>>>(key, query, kstat, mrow, drow);
  k_wvT  <<<dim3(E_/32, E_/32), 256, 0, stream>>>(Wv, wvT);
  // value GEMM: A=token_bf16 (X), writes valT directly (V)
  k_gemm<0><<<dim3((BT_/128)*(E_/128)), 256, 0, stream>>>(X, wvT, bv, nullptr, V);
  // PV: reads valT (V), writes zraw (X; token_bf dead)
  k_pv   <<<dim3((T_/64)*(E_/512)*B_), 512, 0, stream>>>(query, key, mrow, drow, V, X);
  // LN1: X -> V (z1; valT dead)
  k_ln<0><<<dim3(BT_/4), 256, 0, stream>>>(X, g1, b1, (void*)V);
  // gemm2 + residual: A=resid=z1 (V), writes y (X)
  k_gemm<1><<<dim3((BT_/128)*(E_/128)), 256, 0, stream>>>(V, wvT, bv, V, X);
  // LN2 + relu: X -> out (fp32)
  k_ln<1><<<dim3(BT_/4), 256, 0, stream>>>(X, g2, b2, (void*)out);
}

// Round 3
// 482.361 us; speedup vs baseline: 1.8961x; 1.3974x over previous
//
#include <hip/hip_runtime.h>
#include <cstdint>
#include <cstddef>

// Problem shape (fixed by setup_inputs): B=4, T=4096, E=1024
#define B_ 4
#define T_ 4096
#define E_ 1024
#define BT_ (B_*T_)

typedef unsigned short u16;
typedef unsigned int   u32;
typedef __attribute__((ext_vector_type(8))) short bf8;   // 8 x bf16 (4 VGPRs)
typedef __attribute__((ext_vector_type(4))) float f4;

__device__ inline u16 f2bf(float f){            // RNE float->bf16
  u32 x = __float_as_uint(f);
  u32 r = (x + 0x7fffu + ((x >> 16) & 1u)) >> 16;
  return (u16)r;
}
__device__ inline float bf2f(u32 u){ return __uint_as_float(u << 16); }

__device__ inline float wredsum(float v){
  #pragma unroll
  for (int o = 32; o; o >>= 1) v += __shfl_xor(v, o, 64);
  return v;
}

// async global->LDS, 16B per lane; LDS dest is wave-uniform base + lane*16
__device__ inline void gld_lds16(const void* g, void* l){
  __builtin_amdgcn_global_load_lds(
      (const __attribute__((address_space(1))) void*)g,
      (__attribute__((address_space(3))) void*)l, 16, 0, 0);
}

// LDS-only fence + barrier: does NOT drain vmcnt, so global loads issued
// before it stay in flight across the barrier (T3/T4 principle).
__device__ inline void lds_fence_barrier(){
  asm volatile("s_waitcnt lgkmcnt(0)" ::: "memory");
  __builtin_amdgcn_s_barrier();
}

#define LOG2E_ 1.44269504088896340f

// ---- K1: key/query scalars + bf16 token copy (one wave per row) ------------
__global__ __launch_bounds__(256) void k_prep(const float* __restrict__ token,
    const float* __restrict__ Wk, const float* __restrict__ bk,
    const float* __restrict__ Wq, const float* __restrict__ bq,
    float* __restrict__ key, float* __restrict__ query, u16* __restrict__ tokbf){
  int row  = blockIdx.x * 4 + (threadIdx.x >> 6);
  int lane = threadIdx.x & 63;
  const f4* tr = (const f4*)(token + (size_t)row * E_);
  const f4* wk = (const f4*)Wk;
  const f4* wq = (const f4*)Wq;
  float sk = 0.f, sq = 0.f;
  #pragma unroll
  for (int it = 0; it < 4; ++it){
    f4 t = tr[lane + 64*it];
    f4 a = wk[lane + 64*it];
    f4 b = wq[lane + 64*it];
    sk += t.x*a.x + t.y*a.y + t.z*a.z + t.w*a.w;
    sq += t.x*b.x + t.y*b.y + t.z*b.z + t.w*b.w;
    u32 lo = (u32)f2bf(t.x) | ((u32)f2bf(t.y) << 16);
    u32 hi = (u32)f2bf(t.z) | ((u32)f2bf(t.w) << 16);
    uint2 pk; pk.x = lo; pk.y = hi;
    *(uint2*)(tokbf + (size_t)row * E_ + (lane + 64*it)*4) = pk;
  }
  sk = wredsum(sk); sq = wredsum(sq);
  if (lane == 0){ key[row] = sk + bk[0]; query[row] = sq + bq[0]; }
}

// ---- K2: per-batch kmax/kmin ----------------------------------------------
__global__ __launch_bounds__(256) void k_stats(const float* __restrict__ key,
                                               float* __restrict__ kstat){
  int b = blockIdx.x;
  float mx = -3.4e38f, mn = 3.4e38f;
  for (int i = threadIdx.x; i < T_; i += 256){
    float v = key[b*T_ + i];
    mx = fmaxf(mx, v); mn = fminf(mn, v);
  }
  #pragma unroll
  for (int o = 32; o; o >>= 1){
    mx = fmaxf(mx, __shfl_xor(mx, o, 64));
    mn = fminf(mn, __shfl_xor(mn, o, 64));
  }
  __shared__ float smx[4], smn[4];
  int w = threadIdx.x >> 6;
  if ((threadIdx.x & 63) == 0){ smx[w] = mx; smn[w] = mn; }
  __syncthreads();
  if (threadIdx.x == 0){
    mx = fmaxf(fmaxf(smx[0], smx[1]), fmaxf(smx[2], smx[3]));
    mn = fminf(fminf(smn[0], smn[1]), fminf(smn[2], smn[3]));
    kstat[b*2] = mx; kstat[b*2+1] = mn;
  }
}

// ---- K3: softmax row max (analytic) + denominator (one wave per row) -------
__global__ __launch_bounds__(256) void k_denom(const float* __restrict__ key,
    const float* __restrict__ query, const float* __restrict__ kstat,
    float* __restrict__ mrow, float* __restrict__ drow){
  int row  = blockIdx.x * 4 + (threadIdx.x >> 6);
  int lane = threadIdx.x & 63;
  int b = row / T_;
  float q = query[row];
  float m = (q > 0.f) ? q * kstat[b*2] : q * kstat[b*2+1];
  float qL = q * LOG2E_, mL = m * LOG2E_;
  const float* kb = key + (size_t)b * T_;
  float s = 0.f;
  for (int x = lane; x < T_; x += 64) s += exp2f(qL * kb[x] - mL);
  s = wredsum(s);
  if (lane == 0){ mrow[row] = m; drow[row] = s; }
}

// ---- K4: Wv (fp32 [k][n]) -> WvT (bf16 [n][k]) -----------------------------
__global__ __launch_bounds__(256) void k_wvT(const float* __restrict__ Wv,
                                             u16* __restrict__ wvT){
  __shared__ u16 tile[32][33];
  int nt = blockIdx.x, kt = blockIdx.y;
  int tx = threadIdx.x & 31, ty0 = threadIdx.x >> 5;
  #pragma unroll
  for (int p = 0; p < 4; ++p){
    int ty = ty0 + p*8;
    tile[ty][tx] = f2bf(Wv[(size_t)(kt*32+ty)*E_ + nt*32 + tx]);
  }
  __syncthreads();
  #pragma unroll
  for (int p = 0; p < 4; ++p){
    int ty = ty0 + p*8;
    wvT[(size_t)(nt*32+ty)*E_ + kt*32 + tx] = tile[tx][ty];
  }
}

// ---- GEMM: 128x128 tile, 4 waves (2x2, wave tile 64x64), BK=32 -------------
// (unchanged from round 2)
template<int MODE>
__global__ __launch_bounds__(256) void k_gemm(const u16* __restrict__ A,
    const u16* __restrict__ Bt, const float* __restrict__ bias,
    const u16* __restrict__ resid, u16* __restrict__ outp){
  __shared__ __align__(16) u16 lA[128*32];
  __shared__ __align__(16) u16 lB[128*32];
  const int K = E_, N = E_;
  int bid = blockIdx.x;
  int xcd = bid & 7, rr = bid >> 3;
  int m0 = (xcd + (rr >> 3)*8) * 128;
  int n0 = (rr & 7) * 128;
  int tid = threadIdx.x, lane = tid & 63, w = tid >> 6;
  int wr = w >> 1, wc = w & 1, h = lane >> 4, l15 = lane & 15;
  f4 acc[4][4] = {};
  for (int k0 = 0; k0 < K; k0 += 32){
    __syncthreads();
    #pragma unroll
    for (int p = 0; p < 2; ++p){
      int u = p*256 + w*64 + lane;
      int row = u >> 2;
      int sl  = (u & 3) ^ ((row >> 1) & 3);
      const u16* ga = A  + (size_t)(m0 + row) * K + k0 + sl*8;
      const u16* gb = Bt + (size_t)(n0 + row) * K + k0 + sl*8;
      gld_lds16(ga, lA + (size_t)(p*256 + w*64)*8);
      gld_lds16(gb, lB + (size_t)(p*256 + w*64)*8);
    }
    __syncthreads();
    bf8 a[4], bfr[4];
    #pragma unroll
    for (int f = 0; f < 4; ++f){
      int ra = wr*64 + f*16 + l15;
      int rb = wc*64 + f*16 + l15;
      a[f]   = *(const bf8*)&lA[ra*32 + ((h ^ ((ra >> 1) & 3)) & 3)*8];
      bfr[f] = *(const bf8*)&lB[rb*32 + ((h ^ ((rb >> 1) & 3)) & 3)*8];
    }
    #pragma unroll
    for (int fm = 0; fm < 4; ++fm)
    #pragma unroll
    for (int fn = 0; fn < 4; ++fn)
      acc[fm][fn] = __builtin_amdgcn_mfma_f32_16x16x32_bf16(a[fm], bfr[fn], acc[fm][fn], 0,0,0);
  }
  if (MODE == 0){
    #pragma unroll
    for (int fm = 0; fm < 4; ++fm){
      int rowg = m0 + wr*64 + fm*16 + h*4;
      int bb = rowg >> 12;
      int tt = rowg & (T_-1);
      #pragma unroll
      for (int fn = 0; fn < 4; ++fn){
        int col = n0 + wc*64 + fn*16 + l15;
        float bv = bias[col];
        u16 q0 = f2bf(acc[fm][fn][0] + bv);
        u16 q1 = f2bf(acc[fm][fn][1] + bv);
        u16 q2 = f2bf(acc[fm][fn][2] + bv);
        u16 q3 = f2bf(acc[fm][fn][3] + bv);
        uint2 pk; pk.x = (u32)q0 | ((u32)q1 << 16); pk.y = (u32)q2 | ((u32)q3 << 16);
        *(uint2*)(outp + ((size_t)bb*E_ + col)*T_ + tt) = pk;
      }
    }
  } else {
    #pragma unroll
    for (int fm = 0; fm < 4; ++fm)
    #pragma unroll
    for (int fn = 0; fn < 4; ++fn)
    #pragma unroll
    for (int r = 0; r < 4; ++r){
      int row = m0 + wr*64 + fm*16 + h*4 + r;
      int col = n0 + wc*64 + fn*16 + l15;
      float v = acc[fm][fn][r] + bias[col] + bf2f(resid[(size_t)row * N + col]);
      outp[(size_t)row * N + col] = f2bf(v);
    }
  }
}

// ---- K7 v3: PV — z[t][e] = (P @ V)/d --------------------------------------
// Block tile 128(t) x 256(e), 8 waves (2t x 4e), wave tile 64x64, K-step 32.
// P double-buffered in LDS (pad-40 rows, 2-way banks = free). Raw s_barrier +
// lgkmcnt(0) only (never drains vmcnt) -> V global loads issued at phase top
// stay in flight behind P-generation VALU work. No __syncthreads in the loop.
__global__ __launch_bounds__(512, 4) void k_pv(const float* __restrict__ query,
    const float* __restrict__ key, const float* __restrict__ mrow,
    const float* __restrict__ drow, const u16* __restrict__ valT,
    u16* __restrict__ zraw){
  __shared__ __align__(16) u16 ldsA[128*40];
  __shared__ __align__(16) u16 ldsB[128*40];
  int bid = blockIdx.x;                         // 512 blocks
  int panel = (bid & 7) | ((bid >> 8) << 3);    // 0..15 = (b, e-quarter)
  int b  = panel >> 2;
  int e0 = (panel & 3) * 256;
  int t0 = ((bid >> 3) & 31) * 128;
  int tid = threadIdx.x, lane = tid & 63, w = tid >> 6;
  int wr = w >> 2, wc = w & 3, h = lane >> 4, l15 = lane & 15;
  int pr = tid >> 2, ps = tid & 3;              // P-gen: row 0..127, 8 cols each
  float qv = query[b*T_ + t0 + pr] * LOG2E_;
  float mv = mrow [b*T_ + t0 + pr] * LOG2E_;
  const float* kp = key + (size_t)b * T_ + ps*8;
  u16* pdstA = ldsA + pr*40 + ps*8;
  u16* pdstB = ldsB + pr*40 + ps*8;
  const u16* ardA = ldsA + (wr*64 + l15)*40 + h*8;
  const u16* ardB = ldsB + (wr*64 + l15)*40 + h*8;
  const u16* vb = valT + (size_t)b * E_ * T_
                       + (size_t)(e0 + wc*64 + l15) * T_ + h*8;
  f4 acc[4][4] = {};

  auto GENP = [&](int x0, u16* dst){
    f4 k0 = *(const f4*)(kp + x0);
    f4 k1 = *(const f4*)(kp + x0 + 4);
    float e0f = exp2f(qv*k0.x - mv), e1f = exp2f(qv*k0.y - mv);
    float e2f = exp2f(qv*k0.z - mv), e3f = exp2f(qv*k0.w - mv);
    float e4f = exp2f(qv*k1.x - mv), e5f = exp2f(qv*k1.y - mv);
    float e6f = exp2f(qv*k1.z - mv), e7f = exp2f(qv*k1.w - mv);
    uint4 pk;
    pk.x = (u32)f2bf(e0f) | ((u32)f2bf(e1f) << 16);
    pk.y = (u32)f2bf(e2f) | ((u32)f2bf(e3f) << 16);
    pk.z = (u32)f2bf(e4f) | ((u32)f2bf(e5f) << 16);
    pk.w = (u32)f2bf(e6f) | ((u32)f2bf(e7f) << 16);
    *(uint4*)dst = pk;
  };
  auto MM = [&](const u16* ard, int x0){
    bf8 v[4], a[4];
    #pragma unroll
    for (int fn = 0; fn < 4; ++fn)
      v[fn] = *(const bf8*)(vb + (size_t)fn*16*T_ + x0);   // issued first
    #pragma unroll
    for (int fm = 0; fm < 4; ++fm)
      a[fm] = *(const bf8*)(ard + fm*16*40);
    #pragma unroll
    for (int fm = 0; fm < 4; ++fm)
    #pragma unroll
    for (int fn = 0; fn < 4; ++fn)
      acc[fm][fn] = __builtin_amdgcn_mfma_f32_16x16x32_bf16(a[fm], v[fn], acc[fm][fn], 0,0,0);
  };

  GENP(0, pdstA);
  lds_fence_barrier();
  for (int x0 = 0; x0 < T_; x0 += 64){
    // half 1: consume ldsA (k=[x0,x0+32)); produce P(x0+32)->ldsB
    GENP(x0 + 32, pdstB);
    MM(ardA, x0);
    lds_fence_barrier();
    // half 2: consume ldsB; produce P(x0+64)->ldsA (if any)
    if (x0 + 64 < T_) GENP(x0 + 64, pdstA);
    MM(ardB, x0 + 32);
    lds_fence_barrier();
  }

  #pragma unroll
  for (int fm = 0; fm < 4; ++fm){
    #pragma unroll
    for (int r = 0; r < 4; ++r){
      int row = t0 + wr*64 + fm*16 + h*4 + r;
      float inv = 1.f / drow[b*T_ + row];
      #pragma unroll
      for (int fn = 0; fn < 4; ++fn){
        int col = e0 + wc*64 + fn*16 + l15;
        zraw[((size_t)b*T_ + row)*E_ + col] = f2bf(acc[fm][fn][r] * inv);
      }
    }
  }
}

// ---- LN (one wave per row). FINAL=0: bf16 out. FINAL=1: relu -> fp32 out ---
template<int FINAL>
__global__ __launch_bounds__(256) void k_ln(const u16* __restrict__ in,
    const float* __restrict__ g, const float* __restrict__ bt,
    void* __restrict__ outp){
  int row  = blockIdx.x * 4 + (threadIdx.x >> 6);
  int lane = threadIdx.x & 63;
  const u16* r = in + (size_t)row * E_;
  uint4 u0 = *(const uint4*)(r + lane*16);
  uint4 u1 = *(const uint4*)(r + lane*16 + 8);
  u32 uu[8] = {u0.x, u0.y, u0.z, u0.w, u1.x, u1.y, u1.z, u1.w};
  float v[16];
  #pragma unroll
  for (int j = 0; j < 8; ++j){
    v[2*j]   = bf2f(uu[j] & 0xffffu);
    v[2*j+1] = bf2f(uu[j] >> 16);
  }
  float s1 = 0.f, s2 = 0.f;
  #pragma unroll
  for (int j = 0; j < 16; ++j){ s1 += v[j]; s2 += v[j]*v[j]; }
  s1 = wredsum(s1); s2 = wredsum(s2);
  float mean = s1 * (1.f/E_);
  float var  = s2 * (1.f/E_) - mean*mean;
  float rs   = rsqrtf(var + 1e-3f);
  const f4* g4 = (const f4*)g + lane*4;
  const f4* b4 = (const f4*)bt + lane*4;
  float o[16];
  #pragma unroll
  for (int jj = 0; jj < 4; ++jj){
    f4 gg = g4[jj], bb = b4[jj];
    o[4*jj+0] = (v[4*jj+0]-mean)*rs*gg.x + bb.x;
    o[4*jj+1] = (v[4*jj+1]-mean)*rs*gg.y + bb.y;
    o[4*jj+2] = (v[4*jj+2]-mean)*rs*gg.z + bb.z;
    o[4*jj+3] = (v[4*jj+3]-mean)*rs*gg.w + bb.w;
  }
  if (FINAL){
    f4* od = (f4*)((float*)outp + (size_t)row * E_ + lane*16);
    #pragma unroll
    for (int jj = 0; jj < 4; ++jj){
      f4 t;
      t.x = fmaxf(o[4*jj+0], 0.f); t.y = fmaxf(o[4*jj+1], 0.f);
      t.z = fmaxf(o[4*jj+2], 0.f); t.w = fmaxf(o[4*jj+3], 0.f);
      od[jj] = t;
    }
  } else {
    u16* ob = (u16*)outp + (size_t)row * E_ + lane*16;
    u32 pu[8];
    #pragma unroll
    for (int j = 0; j < 8; ++j)
      pu[j] = (u32)f2bf(o[2*j]) | ((u32)f2bf(o[2*j+1]) << 16);
    uint4 w0 = {pu[0], pu[1], pu[2], pu[3]};
    uint4 w1 = {pu[4], pu[5], pu[6], pu[7]};
    *(uint4*)ob       = w0;
    *(uint4*)(ob + 8) = w1;
  }
}

// ---------------------------------------------------------------------------
extern "C" void kernel_launch(void* const* d_in, const int* in_sizes, int n_in,
                              void* d_out, int out_size, void* d_ws, size_t ws_size,
                              hipStream_t stream){
  const float* token = (const float*)d_in[0];
  const float* Wk    = (const float*)d_in[1];
  const float* bk    = (const float*)d_in[2];
  const float* Wq    = (const float*)d_in[3];
  const float* bq    = (const float*)d_in[4];
  const float* Wv    = (const float*)d_in[5];
  const float* bv    = (const float*)d_in[6];
  const float* g1    = (const float*)d_in[7];
  const float* b1    = (const float*)d_in[8];
  const float* g2    = (const float*)d_in[9];
  const float* b2    = (const float*)d_in[10];

  char* ws = (char*)d_ws;
  u16*   wvT   = (u16*)ws;
  float* key   = (float*)(ws + (2u<<20));
  float* query = (float*)(ws + (2u<<20) + (64u<<10));
  float* mrow  = (float*)(ws + (2u<<20) + (128u<<10));
  float* drow  = (float*)(ws + (2u<<20) + (192u<<10));
  float* kstat = (float*)(ws + (2u<<20) + (256u<<10));
  u16* X = (u16*)(ws + (4u<<20));
  u16* V = (u16*)(ws + (36u<<20));
  float* out = (float*)d_out;

  k_prep <<<dim3(BT_/4), 256, 0, stream>>>(token, Wk, bk, Wq, bq, key, query, X);
  k_stats<<<dim3(B_),    256, 0, stream>>>(key, kstat);
  k_denom<<<dim3(BT_/4), 256, 0, stream>>>(key, query, kstat, mrow, drow);
  k_wvT  <<<dim3(E_/32, E_/32), 256, 0, stream>>>(Wv, wvT);
  // value GEMM: A=token_bf16 (X), writes valT directly (V)
  k_gemm<0><<<dim3((BT_/128)*(E_/128)), 256, 0, stream>>>(X, wvT, bv, nullptr, V);
  // PV: reads valT (V), writes zraw (X; token_bf dead)
  k_pv   <<<dim3((T_/128)*(E_/256)*B_), 512, 0, stream>>>(query, key, mrow, drow, V, X);
  // LN1: X -> V (z1; valT dead)
  k_ln<0><<<dim3(BT_/4), 256, 0, stream>>>(X, g1, b1, (void*)V);
  // gemm2 + residual: A=resid=z1 (V), writes y (X)
  k_gemm<1><<<dim3((BT_/128)*(E_/128)), 256, 0, stream>>>(V, wvT, bv, V, X);
  // LN2 + relu: X -> out (fp32)
  k_ln<1><<<dim3(BT_/4), 256, 0, stream>>>(X, g2, b2, (void*)out);
}

// Round 4
// 465.640 us; speedup vs baseline: 1.9642x; 1.0359x over previous
//
#include <hip/hip_runtime.h>
#include <cstdint>
#include <cstddef>

// Problem shape (fixed by setup_inputs): B=4, T=4096, E=1024
#define B_ 4
#define T_ 4096
#define E_ 1024
#define BT_ (B_*T_)

typedef unsigned short u16;
typedef unsigned int   u32;
typedef __attribute__((ext_vector_type(8))) short bf8;   // 8 x bf16 (4 VGPRs)
typedef __attribute__((ext_vector_type(4))) float f4;

__device__ inline u16 f2bf(float f){            // RNE float->bf16
  u32 x = __float_as_uint(f);
  u32 r = (x + 0x7fffu + ((x >> 16) & 1u)) >> 16;
  return (u16)r;
}
__device__ inline float bf2f(u32 u){ return __uint_as_float(u << 16); }

__device__ inline float wredsum(float v){
  #pragma unroll
  for (int o = 32; o; o >>= 1) v += __shfl_xor(v, o, 64);
  return v;
}

// raw hardware exp2 (no ocml denormal fixup); safe here: arg <= 0, underflow->0
__device__ inline float hw_exp2(float x){
#if __has_builtin(__builtin_amdgcn_exp2f)
  return __builtin_amdgcn_exp2f(x);
#else
  return exp2f(x);
#endif
}

// v_cvt_pk_bf16_f32: D[15:0]=bf16(a), D[31:16]=bf16(b)  (RNE)
__device__ inline u32 cvt_pk_bf16(float a, float b){
  u32 r;
  asm("v_cvt_pk_bf16_f32 %0, %1, %2" : "=v"(r) : "v"(a), "v"(b));
  return r;
}

// async global->LDS, 16B per lane; LDS dest is wave-uniform base + lane*16
__device__ inline void gld_lds16(const void* g, void* l){
  __builtin_amdgcn_global_load_lds(
      (const __attribute__((address_space(1))) void*)g,
      (__attribute__((address_space(3))) void*)l, 16, 0, 0);
}

#define LOG2E_ 1.44269504088896340f

// ---- K1: key/query scalars + bf16 token copy (one wave per row) ------------
__global__ __launch_bounds__(256) void k_prep(const float* __restrict__ token,
    const float* __restrict__ Wk, const float* __restrict__ bk,
    const float* __restrict__ Wq, const float* __restrict__ bq,
    float* __restrict__ key, float* __restrict__ query, u16* __restrict__ tokbf){
  int row  = blockIdx.x * 4 + (threadIdx.x >> 6);
  int lane = threadIdx.x & 63;
  const f4* tr = (const f4*)(token + (size_t)row * E_);
  const f4* wk = (const f4*)Wk;
  const f4* wq = (const f4*)Wq;
  float sk = 0.f, sq = 0.f;
  #pragma unroll
  for (int it = 0; it < 4; ++it){
    f4 t = tr[lane + 64*it];
    f4 a = wk[lane + 64*it];
    f4 b = wq[lane + 64*it];
    sk += t.x*a.x + t.y*a.y + t.z*a.z + t.w*a.w;
    sq += t.x*b.x + t.y*b.y + t.z*b.z + t.w*b.w;
    u32 lo = (u32)f2bf(t.x) | ((u32)f2bf(t.y) << 16);
    u32 hi = (u32)f2bf(t.z) | ((u32)f2bf(t.w) << 16);
    uint2 pk; pk.x = lo; pk.y = hi;
    *(uint2*)(tokbf + (size_t)row * E_ + (lane + 64*it)*4) = pk;
  }
  sk = wredsum(sk); sq = wredsum(sq);
  if (lane == 0){ key[row] = sk + bk[0]; query[row] = sq + bq[0]; }
}

// ---- K2: per-batch kmax/kmin ----------------------------------------------
__global__ __launch_bounds__(256) void k_stats(const float* __restrict__ key,
                                               float* __restrict__ kstat){
  int b = blockIdx.x;
  float mx = -3.4e38f, mn = 3.4e38f;
  for (int i = threadIdx.x; i < T_; i += 256){
    float v = key[b*T_ + i];
    mx = fmaxf(mx, v); mn = fminf(mn, v);
  }
  #pragma unroll
  for (int o = 32; o; o >>= 1){
    mx = fmaxf(mx, __shfl_xor(mx, o, 64));
    mn = fminf(mn, __shfl_xor(mn, o, 64));
  }
  __shared__ float smx[4], smn[4];
  int w = threadIdx.x >> 6;
  if ((threadIdx.x & 63) == 0){ smx[w] = mx; smn[w] = mn; }
  __syncthreads();
  if (threadIdx.x == 0){
    mx = fmaxf(fmaxf(smx[0], smx[1]), fmaxf(smx[2], smx[3]));
    mn = fminf(fminf(smn[0], smn[1]), fminf(smn[2], smn[3]));
    kstat[b*2] = mx; kstat[b*2+1] = mn;
  }
}

// ---- K3: softmax row max (analytic) + denominator (one wave per row) -------
__global__ __launch_bounds__(256) void k_denom(const float* __restrict__ key,
    const float* __restrict__ query, const float* __restrict__ kstat,
    float* __restrict__ mrow, float* __restrict__ drow){
  int row  = blockIdx.x * 4 + (threadIdx.x >> 6);
  int lane = threadIdx.x & 63;
  int b = row / T_;
  float q = query[row];
  float m = (q > 0.f) ? q * kstat[b*2] : q * kstat[b*2+1];
  float qL = q * LOG2E_, mL = m * LOG2E_;
  const float* kb = key + (size_t)b * T_;
  float s = 0.f;
  for (int x = lane; x < T_; x += 64) s += hw_exp2(qL * kb[x] - mL);
  s = wredsum(s);
  if (lane == 0){ mrow[row] = m; drow[row] = s; }
}

// ---- K4: Wv (fp32 [k][n]) -> WvT (bf16 [n][k]) -----------------------------
__global__ __launch_bounds__(256) void k_wvT(const float* __restrict__ Wv,
                                             u16* __restrict__ wvT){
  __shared__ u16 tile[32][33];
  int nt = blockIdx.x, kt = blockIdx.y;
  int tx = threadIdx.x & 31, ty0 = threadIdx.x >> 5;
  #pragma unroll
  for (int p = 0; p < 4; ++p){
    int ty = ty0 + p*8;
    tile[ty][tx] = f2bf(Wv[(size_t)(kt*32+ty)*E_ + nt*32 + tx]);
  }
  __syncthreads();
  #pragma unroll
  for (int p = 0; p < 4; ++p){
    int ty = ty0 + p*8;
    wvT[(size_t)(nt*32+ty)*E_ + kt*32 + tx] = tile[tx][ty];
  }
}

// ---- GEMM: 128x128 tile, 4 waves (2x2, wave tile 64x64), BK=32 -------------
// (unchanged, validated in rounds 2-3)
template<int MODE>
__global__ __launch_bounds__(256) void k_gemm(const u16* __restrict__ A,
    const u16* __restrict__ Bt, const float* __restrict__ bias,
    const u16* __restrict__ resid, u16* __restrict__ outp){
  __shared__ __align__(16) u16 lA[128*32];
  __shared__ __align__(16) u16 lB[128*32];
  const int K = E_, N = E_;
  int bid = blockIdx.x;
  int xcd = bid & 7, rr = bid >> 3;
  int m0 = (xcd + (rr >> 3)*8) * 128;
  int n0 = (rr & 7) * 128;
  int tid = threadIdx.x, lane = tid & 63, w = tid >> 6;
  int wr = w >> 1, wc = w & 1, h = lane >> 4, l15 = lane & 15;
  f4 acc[4][4] = {};
  for (int k0 = 0; k0 < K; k0 += 32){
    __syncthreads();
    #pragma unroll
    for (int p = 0; p < 2; ++p){
      int u = p*256 + w*64 + lane;
      int row = u >> 2;
      int sl  = (u & 3) ^ ((row >> 1) & 3);
      const u16* ga = A  + (size_t)(m0 + row) * K + k0 + sl*8;
      const u16* gb = Bt + (size_t)(n0 + row) * K + k0 + sl*8;
      gld_lds16(ga, lA + (size_t)(p*256 + w*64)*8);
      gld_lds16(gb, lB + (size_t)(p*256 + w*64)*8);
    }
    __syncthreads();
    bf8 a[4], bfr[4];
    #pragma unroll
    for (int f = 0; f < 4; ++f){
      int ra = wr*64 + f*16 + l15;
      int rb = wc*64 + f*16 + l15;
      a[f]   = *(const bf8*)&lA[ra*32 + ((h ^ ((ra >> 1) & 3)) & 3)*8];
      bfr[f] = *(const bf8*)&lB[rb*32 + ((h ^ ((rb >> 1) & 3)) & 3)*8];
    }
    #pragma unroll
    for (int fm = 0; fm < 4; ++fm)
    #pragma unroll
    for (int fn = 0; fn < 4; ++fn)
      acc[fm][fn] = __builtin_amdgcn_mfma_f32_16x16x32_bf16(a[fm], bfr[fn], acc[fm][fn], 0,0,0);
  }
  if (MODE == 0){
    #pragma unroll
    for (int fm = 0; fm < 4; ++fm){
      int rowg = m0 + wr*64 + fm*16 + h*4;
      int bb = rowg >> 12;
      int tt = rowg & (T_-1);
      #pragma unroll
      for (int fn = 0; fn < 4; ++fn){
        int col = n0 + wc*64 + fn*16 + l15;
        float bv = bias[col];
        u16 q0 = f2bf(acc[fm][fn][0] + bv);
        u16 q1 = f2bf(acc[fm][fn][1] + bv);
        u16 q2 = f2bf(acc[fm][fn][2] + bv);
        u16 q3 = f2bf(acc[fm][fn][3] + bv);
        uint2 pk; pk.x = (u32)q0 | ((u32)q1 << 16); pk.y = (u32)q2 | ((u32)q3 << 16);
        *(uint2*)(outp + ((size_t)bb*E_ + col)*T_ + tt) = pk;
      }
    }
  } else {
    #pragma unroll
    for (int fm = 0; fm < 4; ++fm)
    #pragma unroll
    for (int fn = 0; fn < 4; ++fn)
    #pragma unroll
    for (int r = 0; r < 4; ++r){
      int row = m0 + wr*64 + fm*16 + h*4 + r;
      int col = n0 + wc*64 + fn*16 + l15;
      float v = acc[fm][fn][r] + bias[col] + bf2f(resid[(size_t)row * N + col]);
      outp[(size_t)row * N + col] = f2bf(v);
    }
  }
}

// ---- K7 v4: PV — z[t][e] = (P @ V)/d;  NO LDS, NO BARRIERS ------------------
// Each wave independently owns a 64(t) x 64(e) output tile. P A-fragments are
// generated per-lane in registers: lane needs P[row=fm*16+l15][k=x0+8h+j] =
// exp2(qv[fm]*k[j] - mv[fm]) -- 32 v_exp per 32-K step, packed with
// v_cvt_pk_bf16_f32. V and K register-prefetched one step ahead, so after
// warmup no phase waits on memory. Waves free-run -> latency hidden by TLP.
__global__ __launch_bounds__(256) void k_pv(const float* __restrict__ query,
    const float* __restrict__ key, const float* __restrict__ mrow,
    const float* __restrict__ drow, const u16* __restrict__ valT,
    u16* __restrict__ zraw){
  int bid = blockIdx.x;                         // 1024 blocks x 4 waves
  int panel = (bid & 7) | ((bid >> 9) << 3);    // 0..15 = (b, e-quarter)
  int tb    = (bid >> 3) & 63;                  // t-block (64 rows)
  int b  = panel >> 2;
  int e0 = (panel & 3) * 256;
  int w = threadIdx.x >> 6, lane = threadIdx.x & 63;
  int h = lane >> 4, l15 = lane & 15;
  int ebase = e0 + w*64;

  float qv[4], mv[4];
  #pragma unroll
  for (int fm = 0; fm < 4; ++fm){
    int row = tb*64 + fm*16 + l15;
    qv[fm] = query[b*T_ + row] * LOG2E_;
    mv[fm] = mrow [b*T_ + row] * LOG2E_;
  }
  const float* kp = key + (size_t)b * T_ + h*8;  // lane's 8 k-cols at x0+8h
  const u16*   vb = valT + (size_t)b * E_ * T_
                         + (size_t)(ebase + l15) * T_ + h*8;
  f4 acc[4][4] = {};

  // prefetch step 0
  f4 ka = *(const f4*)(kp);
  f4 kc = *(const f4*)(kp + 4);
  bf8 vr0 = *(const bf8*)(vb);
  bf8 vr1 = *(const bf8*)(vb + (size_t)16*T_);
  bf8 vr2 = *(const bf8*)(vb + (size_t)32*T_);
  bf8 vr3 = *(const bf8*)(vb + (size_t)48*T_);

  for (int x0 = 0; x0 < T_; x0 += 32){
    // issue next-step prefetch (stays in flight behind compute)
    f4 kna, knc; bf8 vn0, vn1, vn2, vn3;
    if (x0 + 32 < T_){
      kna = *(const f4*)(kp + x0 + 32);
      knc = *(const f4*)(kp + x0 + 36);
      vn0 = *(const bf8*)(vb + x0 + 32);
      vn1 = *(const bf8*)(vb + (size_t)16*T_ + x0 + 32);
      vn2 = *(const bf8*)(vb + (size_t)32*T_ + x0 + 32);
      vn3 = *(const bf8*)(vb + (size_t)48*T_ + x0 + 32);
    }
    // generate A-fragments from (ka,kc) -- ready since last step
    bf8 af[4];
    #pragma unroll
    for (int fm = 0; fm < 4; ++fm){
      float q = qv[fm], m = mv[fm];
      float p0 = hw_exp2(q*ka.x - m), p1 = hw_exp2(q*ka.y - m);
      float p2 = hw_exp2(q*ka.z - m), p3 = hw_exp2(q*ka.w - m);
      float p4 = hw_exp2(q*kc.x - m), p5 = hw_exp2(q*kc.y - m);
      float p6 = hw_exp2(q*kc.z - m), p7 = hw_exp2(q*kc.w - m);
      u32 d0 = cvt_pk_bf16(p0, p1);
      u32 d1 = cvt_pk_bf16(p2, p3);
      u32 d2 = cvt_pk_bf16(p4, p5);
      u32 d3 = cvt_pk_bf16(p6, p7);
      uint4 pk; pk.x = d0; pk.y = d1; pk.z = d2; pk.w = d3;
      af[fm] = *(bf8*)&pk;
    }
    #pragma unroll
    for (int fm = 0; fm < 4; ++fm){
      acc[fm][0] = __builtin_amdgcn_mfma_f32_16x16x32_bf16(af[fm], vr0, acc[fm][0], 0,0,0);
      acc[fm][1] = __builtin_amdgcn_mfma_f32_16x16x32_bf16(af[fm], vr1, acc[fm][1], 0,0,0);
      acc[fm][2] = __builtin_amdgcn_mfma_f32_16x16x32_bf16(af[fm], vr2, acc[fm][2], 0,0,0);
      acc[fm][3] = __builtin_amdgcn_mfma_f32_16x16x32_bf16(af[fm], vr3, acc[fm][3], 0,0,0);
    }
    ka = kna; kc = knc;
    vr0 = vn0; vr1 = vn1; vr2 = vn2; vr3 = vn3;
  }

  #pragma unroll
  for (int fm = 0; fm < 4; ++fm){
    #pragma unroll
    for (int r = 0; r < 4; ++r){
      int row = tb*64 + fm*16 + h*4 + r;
      float inv = 1.f / drow[b*T_ + row];
      #pragma unroll
      for (int fn = 0; fn < 4; ++fn){
        int col = ebase + fn*16 + l15;
        zraw[((size_t)b*T_ + row)*E_ + col] = f2bf(acc[fm][fn][r] * inv);
      }
    }
  }
}

// ---- LN (one wave per row). FINAL=0: bf16 out. FINAL=1: relu -> fp32 out ---
template<int FINAL>
__global__ __launch_bounds__(256) void k_ln(const u16* __restrict__ in,
    const float* __restrict__ g, const float* __restrict__ bt,
    void* __restrict__ outp){
  int row  = blockIdx.x * 4 + (threadIdx.x >> 6);
  int lane = threadIdx.x & 63;
  const u16* r = in + (size_t)row * E_;
  uint4 u0 = *(const uint4*)(r + lane*16);
  uint4 u1 = *(const uint4*)(r + lane*16 + 8);
  u32 uu[8] = {u0.x, u0.y, u0.z, u0.w, u1.x, u1.y, u1.z, u1.w};
  float v[16];
  #pragma unroll
  for (int j = 0; j < 8; ++j){
    v[2*j]   = bf2f(uu[j] & 0xffffu);
    v[2*j+1] = bf2f(uu[j] >> 16);
  }
  float s1 = 0.f, s2 = 0.f;
  #pragma unroll
  for (int j = 0; j < 16; ++j){ s1 += v[j]; s2 += v[j]*v[j]; }
  s1 = wredsum(s1); s2 = wredsum(s2);
  float mean = s1 * (1.f/E_);
  float var  = s2 * (1.f/E_) - mean*mean;
  float rs   = rsqrtf(var + 1e-3f);
  const f4* g4 = (const f4*)g + lane*4;
  const f4* b4 = (const f4*)bt + lane*4;
  float o[16];
  #pragma unroll
  for (int jj = 0; jj < 4; ++jj){
    f4 gg = g4[jj], bb = b4[jj];
    o[4*jj+0] = (v[4*jj+0]-mean)*rs*gg.x + bb.x;
    o[4*jj+1] = (v[4*jj+1]-mean)*rs*gg.y + bb.y;
    o[4*jj+2] = (v[4*jj+2]-mean)*rs*gg.z + bb.z;
    o[4*jj+3] = (v[4*jj+3]-mean)*rs*gg.w + bb.w;
  }
  if (FINAL){
    f4* od = (f4*)((float*)outp + (size_t)row * E_ + lane*16);
    #pragma unroll
    for (int jj = 0; jj < 4; ++jj){
      f4 t;
      t.x = fmaxf(o[4*jj+0], 0.f); t.y = fmaxf(o[4*jj+1], 0.f);
      t.z = fmaxf(o[4*jj+2], 0.f); t.w = fmaxf(o[4*jj+3], 0.f);
      od[jj] = t;
    }
  } else {
    u16* ob = (u16*)outp + (size_t)row * E_ + lane*16;
    u32 pu[8];
    #pragma unroll
    for (int j = 0; j < 8; ++j)
      pu[j] = (u32)f2bf(o[2*j]) | ((u32)f2bf(o[2*j+1]) << 16);
    uint4 w0 = {pu[0], pu[1], pu[2], pu[3]};
    uint4 w1 = {pu[4], pu[5], pu[6], pu[7]};
    *(uint4*)ob       = w0;
    *(uint4*)(ob + 8) = w1;
  }
}

// ---------------------------------------------------------------------------
extern "C" void kernel_launch(void* const* d_in, const int* in_sizes, int n_in,
                              void* d_out, int out_size, void* d_ws, size_t ws_size,
                              hipStream_t stream){
  const float* token = (const float*)d_in[0];
  const float* Wk    = (const float*)d_in[1];
  const float* bk    = (const float*)d_in[2];
  const float* Wq    = (const float*)d_in[3];
  const float* bq    = (const float*)d_in[4];
  const float* Wv    = (const float*)d_in[5];
  const float* bv    = (const float*)d_in[6];
  const float* g1    = (const float*)d_in[7];
  const float* b1    = (const float*)d_in[8];
  const float* g2    = (const float*)d_in[9];
  const float* b2    = (const float*)d_in[10];

  char* ws = (char*)d_ws;
  u16*   wvT   = (u16*)ws;
  float* key   = (float*)(ws + (2u<<20));
  float* query = (float*)(ws + (2u<<20) + (64u<<10));
  float* mrow  = (float*)(ws + (2u<<20) + (128u<<10));
  float* drow  = (float*)(ws + (2u<<20) + (192u<<10));
  float* kstat = (float*)(ws + (2u<<20) + (256u<<10));
  u16* X = (u16*)(ws + (4u<<20));
  u16* V = (u16*)(ws + (36u<<20));
  float* out = (float*)d_out;

  k_prep <<<dim3(BT_/4), 256, 0, stream>>>(token, Wk, bk, Wq, bq, key, query, X);
  k_stats<<<dim3(B_),    256, 0, stream>>>(key, kstat);
  k_denom<<<dim3(BT_/4), 256, 0, stream>>>(key, query, kstat, mrow, drow);
  k_wvT  <<<dim3(E_/32, E_/32), 256, 0, stream>>>(Wv, wvT);
  // value GEMM: A=token_bf16 (X), writes valT directly (V)
  k_gemm<0><<<dim3((BT_/128)*(E_/128)), 256, 0, stream>>>(X, wvT, bv, nullptr, V);
  // PV: reads valT (V), writes zraw (X; token_bf dead)
  k_pv   <<<dim3((T_/64)*(E_/256)*B_), 256, 0, stream>>>(query, key, mrow, drow, V, X);
  // LN1: X -> V (z1; valT dead)
  k_ln<0><<<dim3(BT_/4), 256, 0, stream>>>(X, g1, b1, (void*)V);
  // gemm2 + residual: A=resid=z1 (V), writes y (X)
  k_gemm<1><<<dim3((BT_/128)*(E_/128)), 256, 0, stream>>>(V, wvT, bv, V, X);
  // LN2 + relu: X -> out (fp32)
  k_ln<1><<<dim3(BT_/4), 256, 0, stream>>>(X, g2, b2, (void*)out);
}

// Round 6
// 453.249 us; speedup vs baseline: 2.0179x; 1.0273x over previous
//
#include <hip/hip_runtime.h>
#include <cstdint>
#include <cstddef>

// Problem shape (fixed by setup_inputs): B=4, T=4096, E=1024
#define B_ 4
#define T_ 4096
#define E_ 1024
#define BT_ (B_*T_)

typedef unsigned short u16;
typedef unsigned int   u32;
typedef __attribute__((ext_vector_type(8))) short bf8;   // 8 x bf16 (4 VGPRs)
typedef __attribute__((ext_vector_type(4))) float f4;

union punAB { uint4 u; bf8 v; };   // legal type-pun (union, clang-supported)

__device__ inline u16 f2bf(float f){            // RNE float->bf16
  u32 x = __float_as_uint(f);
  u32 r = (x + 0x7fffu + ((x >> 16) & 1u)) >> 16;
  return (u16)r;
}
__device__ inline float bf2f(u32 u){ return __uint_as_float(u << 16); }

__device__ inline float wredsum(float v){
  #pragma unroll
  for (int o = 32; o; o >>= 1) v += __shfl_xor(v, o, 64);
  return v;
}

// raw hardware exp2 (no ocml denormal fixup); safe here: arg <= 0, underflow->0
__device__ inline float hw_exp2(float x){
#if __has_builtin(__builtin_amdgcn_exp2f)
  return __builtin_amdgcn_exp2f(x);
#else
  return exp2f(x);
#endif
}

// v_cvt_pk_bf16_f32: D[15:0]=bf16(a), D[31:16]=bf16(b)  (RNE)
__device__ inline u32 cvt_pk_bf16(float a, float b){
  u32 r;
  asm("v_cvt_pk_bf16_f32 %0, %1, %2" : "=v"(r) : "v"(a), "v"(b));
  return r;
}

// async global->LDS, 16B per lane; LDS dest is wave-uniform base + lane*16
__device__ inline void gld_lds16(const void* g, void* l){
  __builtin_amdgcn_global_load_lds(
      (const __attribute__((address_space(1))) void*)g,
      (__attribute__((address_space(3))) void*)l, 16, 0, 0);
}

#define LOG2E_ 1.44269504088896340f

// ---- K1: key/query scalars + bf16 token copy (one wave per row) ------------
__global__ __launch_bounds__(256) void k_prep(const float* __restrict__ token,
    const float* __restrict__ Wk, const float* __restrict__ bk,
    const float* __restrict__ Wq, const float* __restrict__ bq,
    float* __restrict__ key, float* __restrict__ query, u16* __restrict__ tokbf){
  int row  = blockIdx.x * 4 + (threadIdx.x >> 6);
  int lane = threadIdx.x & 63;
  const f4* tr = (const f4*)(token + (size_t)row * E_);
  const f4* wk = (const f4*)Wk;
  const f4* wq = (const f4*)Wq;
  float sk = 0.f, sq = 0.f;
  #pragma unroll
  for (int it = 0; it < 4; ++it){
    f4 t = tr[lane + 64*it];
    f4 a = wk[lane + 64*it];
    f4 b = wq[lane + 64*it];
    sk += t.x*a.x + t.y*a.y + t.z*a.z + t.w*a.w;
    sq += t.x*b.x + t.y*b.y + t.z*b.z + t.w*b.w;
    u32 lo = (u32)f2bf(t.x) | ((u32)f2bf(t.y) << 16);
    u32 hi = (u32)f2bf(t.z) | ((u32)f2bf(t.w) << 16);
    uint2 pk; pk.x = lo; pk.y = hi;
    *(uint2*)(tokbf + (size_t)row * E_ + (lane + 64*it)*4) = pk;
  }
  sk = wredsum(sk); sq = wredsum(sq);
  if (lane == 0){ key[row] = sk + bk[0]; query[row] = sq + bq[0]; }
}

// ---- K2: per-batch kmax/kmin ----------------------------------------------
__global__ __launch_bounds__(256) void k_stats(const float* __restrict__ key,
                                               float* __restrict__ kstat){
  int b = blockIdx.x;
  float mx = -3.4e38f, mn = 3.4e38f;
  for (int i = threadIdx.x; i < T_; i += 256){
    float v = key[b*T_ + i];
    mx = fmaxf(mx, v); mn = fminf(mn, v);
  }
  #pragma unroll
  for (int o = 32; o; o >>= 1){
    mx = fmaxf(mx, __shfl_xor(mx, o, 64));
    mn = fminf(mn, __shfl_xor(mn, o, 64));
  }
  __shared__ float smx[4], smn[4];
  int w = threadIdx.x >> 6;
  if ((threadIdx.x & 63) == 0){ smx[w] = mx; smn[w] = mn; }
  __syncthreads();
  if (threadIdx.x == 0){
    mx = fmaxf(fmaxf(smx[0], smx[1]), fmaxf(smx[2], smx[3]));
    mn = fminf(fminf(smn[0], smn[1]), fminf(smn[2], smn[3]));
    kstat[b*2] = mx; kstat[b*2+1] = mn;
  }
}

// ---- K3: softmax row max (analytic) + denominator (one wave per row) -------
__global__ __launch_bounds__(256) void k_denom(const float* __restrict__ key,
    const float* __restrict__ query, const float* __restrict__ kstat,
    float* __restrict__ mrow, float* __restrict__ drow){
  int row  = blockIdx.x * 4 + (threadIdx.x >> 6);
  int lane = threadIdx.x & 63;
  int b = row / T_;
  float q = query[row];
  float m = (q > 0.f) ? q * kstat[b*2] : q * kstat[b*2+1];
  float qL = q * LOG2E_, mL = m * LOG2E_;
  const float* kb = key + (size_t)b * T_;
  float s = 0.f;
  for (int x = lane; x < T_; x += 64) s += hw_exp2(qL * kb[x] - mL);
  s = wredsum(s);
  if (lane == 0){ mrow[row] = m; drow[row] = s; }
}

// ---- K4: Wv (fp32 [k][n]) -> WvT (bf16 [n][k]) -----------------------------
__global__ __launch_bounds__(256) void k_wvT(const float* __restrict__ Wv,
                                             u16* __restrict__ wvT){
  __shared__ u16 tile[32][33];
  int nt = blockIdx.x, kt = blockIdx.y;
  int tx = threadIdx.x & 31, ty0 = threadIdx.x >> 5;
  #pragma unroll
  for (int p = 0; p < 4; ++p){
    int ty = ty0 + p*8;
    tile[ty][tx] = f2bf(Wv[(size_t)(kt*32+ty)*E_ + nt*32 + tx]);
  }
  __syncthreads();
  #pragma unroll
  for (int p = 0; p < 4; ++p){
    int ty = ty0 + p*8;
    wvT[(size_t)(nt*32+ty)*E_ + kt*32 + tx] = tile[tx][ty];
  }
}

// ---- GEMM: 128x128 tile, 4 waves (2x2, wave tile 64x64), BK=32 -------------
// (unchanged, validated in rounds 2-4)
template<int MODE>
__global__ __launch_bounds__(256) void k_gemm(const u16* __restrict__ A,
    const u16* __restrict__ Bt, const float* __restrict__ bias,
    const u16* __restrict__ resid, u16* __restrict__ outp){
  __shared__ __align__(16) u16 lA[128*32];
  __shared__ __align__(16) u16 lB[128*32];
  const int K = E_, N = E_;
  int bid = blockIdx.x;
  int xcd = bid & 7, rr = bid >> 3;
  int m0 = (xcd + (rr >> 3)*8) * 128;
  int n0 = (rr & 7) * 128;
  int tid = threadIdx.x, lane = tid & 63, w = tid >> 6;
  int wr = w >> 1, wc = w & 1, h = lane >> 4, l15 = lane & 15;
  f4 acc[4][4] = {};
  for (int k0 = 0; k0 < K; k0 += 32){
    __syncthreads();
    #pragma unroll
    for (int p = 0; p < 2; ++p){
      int u = p*256 + w*64 + lane;
      int row = u >> 2;
      int sl  = (u & 3) ^ ((row >> 1) & 3);
      const u16* ga = A  + (size_t)(m0 + row) * K + k0 + sl*8;
      const u16* gb = Bt + (size_t)(n0 + row) * K + k0 + sl*8;
      gld_lds16(ga, lA + (size_t)(p*256 + w*64)*8);
      gld_lds16(gb, lB + (size_t)(p*256 + w*64)*8);
    }
    __syncthreads();
    bf8 a[4], bfr[4];
    #pragma unroll
    for (int f = 0; f < 4; ++f){
      int ra = wr*64 + f*16 + l15;
      int rb = wc*64 + f*16 + l15;
      a[f]   = *(const bf8*)&lA[ra*32 + ((h ^ ((ra >> 1) & 3)) & 3)*8];
      bfr[f] = *(const bf8*)&lB[rb*32 + ((h ^ ((rb >> 1) & 3)) & 3)*8];
    }
    #pragma unroll
    for (int fm = 0; fm < 4; ++fm)
    #pragma unroll
    for (int fn = 0; fn < 4; ++fn)
      acc[fm][fn] = __builtin_amdgcn_mfma_f32_16x16x32_bf16(a[fm], bfr[fn], acc[fm][fn], 0,0,0);
  }
  if (MODE == 0){
    #pragma unroll
    for (int fm = 0; fm < 4; ++fm){
      int rowg = m0 + wr*64 + fm*16 + h*4;
      int bb = rowg >> 12;
      int tt = rowg & (T_-1);
      #pragma unroll
      for (int fn = 0; fn < 4; ++fn){
        int col = n0 + wc*64 + fn*16 + l15;
        float bv = bias[col];
        u16 q0 = f2bf(acc[fm][fn][0] + bv);
        u16 q1 = f2bf(acc[fm][fn][1] + bv);
        u16 q2 = f2bf(acc[fm][fn][2] + bv);
        u16 q3 = f2bf(acc[fm][fn][3] + bv);
        uint2 pk; pk.x = (u32)q0 | ((u32)q1 << 16); pk.y = (u32)q2 | ((u32)q3 << 16);
        *(uint2*)(outp + ((size_t)bb*E_ + col)*T_ + tt) = pk;
      }
    }
  } else {
    #pragma unroll
    for (int fm = 0; fm < 4; ++fm)
    #pragma unroll
    for (int fn = 0; fn < 4; ++fn)
    #pragma unroll
    for (int r = 0; r < 4; ++r){
      int row = m0 + wr*64 + fm*16 + h*4 + r;
      int col = n0 + wc*64 + fn*16 + l15;
      float v = acc[fm][fn][r] + bias[col] + bf2f(resid[(size_t)row * N + col]);
      outp[(size_t)row * N + col] = f2bf(v);
    }
  }
}

// ---- K7 v6: PV — wave = 64t x 128e; round-4 proven loop shape, widened ------
// No LDS, no barriers, no lambda. Depth-1 register prefetch with copies
// (exactly the structure that passed in round 4), masked wrap keeps all loads
// defined. Exp:MFMA per 32-K step = 32:32. Plain launch_bounds(256).
__global__ __launch_bounds__(256) void k_pv(const float* __restrict__ query,
    const float* __restrict__ key, const float* __restrict__ mrow,
    const float* __restrict__ drow, const u16* __restrict__ valT,
    u16* __restrict__ zraw){
  int bid = blockIdx.x;                         // 512 blocks
  int panel = bid & 7;                          // (b, e-half)
  int b  = panel >> 1;
  int e0 = (panel & 1) * 512;
  int t0 = (bid >> 3) * 64;                     // t-block
  int w = threadIdx.x >> 6, lane = threadIdx.x & 63;
  int h = lane >> 4, l15 = lane & 15;
  int ebase = e0 + w*128;

  float qv[4], mv[4];
  #pragma unroll
  for (int fm = 0; fm < 4; ++fm){
    int row = t0 + fm*16 + l15;
    qv[fm] = query[b*T_ + row] * LOG2E_;
    mv[fm] = mrow [b*T_ + row] * LOG2E_;
  }
  const float* kp = key + (size_t)b * T_ + h*8;  // lane's 8 k-cols at x0+8h
  const u16*   vb = valT + (size_t)b * E_ * T_
                         + (size_t)(ebase + l15) * T_ + h*8;
  f4 acc[4][8] = {};

  // prefetch step 0
  f4 ka = *(const f4*)(kp);
  f4 kc = *(const f4*)(kp + 4);
  bf8 vr0 = *(const bf8*)(vb);
  bf8 vr1 = *(const bf8*)(vb + (size_t)16*T_);
  bf8 vr2 = *(const bf8*)(vb + (size_t)32*T_);
  bf8 vr3 = *(const bf8*)(vb + (size_t)48*T_);
  bf8 vr4 = *(const bf8*)(vb + (size_t)64*T_);
  bf8 vr5 = *(const bf8*)(vb + (size_t)80*T_);
  bf8 vr6 = *(const bf8*)(vb + (size_t)96*T_);
  bf8 vr7 = *(const bf8*)(vb + (size_t)112*T_);

  for (int x0 = 0; x0 < T_; x0 += 32){
    // issue next-step prefetch (masked wrap on last iter; values unused then)
    int xn = (x0 + 32) & (T_ - 1);
    f4 kna = *(const f4*)(kp + xn);
    f4 knc = *(const f4*)(kp + xn + 4);
    bf8 vn0 = *(const bf8*)(vb + xn);
    bf8 vn1 = *(const bf8*)(vb + (size_t)16*T_ + xn);
    bf8 vn2 = *(const bf8*)(vb + (size_t)32*T_ + xn);
    bf8 vn3 = *(const bf8*)(vb + (size_t)48*T_ + xn);
    bf8 vn4 = *(const bf8*)(vb + (size_t)64*T_ + xn);
    bf8 vn5 = *(const bf8*)(vb + (size_t)80*T_ + xn);
    bf8 vn6 = *(const bf8*)(vb + (size_t)96*T_ + xn);
    bf8 vn7 = *(const bf8*)(vb + (size_t)112*T_ + xn);
    // compute on current set (ready since last step)
    #pragma unroll
    for (int fm = 0; fm < 4; ++fm){
      float q = qv[fm], m = mv[fm];
      float p0 = hw_exp2(q*ka.x - m), p1 = hw_exp2(q*ka.y - m);
      float p2 = hw_exp2(q*ka.z - m), p3 = hw_exp2(q*ka.w - m);
      float p4 = hw_exp2(q*kc.x - m), p5 = hw_exp2(q*kc.y - m);
      float p6 = hw_exp2(q*kc.z - m), p7 = hw_exp2(q*kc.w - m);
      punAB pa;
      pa.u.x = cvt_pk_bf16(p0, p1);
      pa.u.y = cvt_pk_bf16(p2, p3);
      pa.u.z = cvt_pk_bf16(p4, p5);
      pa.u.w = cvt_pk_bf16(p6, p7);
      bf8 af = pa.v;
      acc[fm][0] = __builtin_amdgcn_mfma_f32_16x16x32_bf16(af, vr0, acc[fm][0], 0,0,0);
      acc[fm][1] = __builtin_amdgcn_mfma_f32_16x16x32_bf16(af, vr1, acc[fm][1], 0,0,0);
      acc[fm][2] = __builtin_amdgcn_mfma_f32_16x16x32_bf16(af, vr2, acc[fm][2], 0,0,0);
      acc[fm][3] = __builtin_amdgcn_mfma_f32_16x16x32_bf16(af, vr3, acc[fm][3], 0,0,0);
      acc[fm][4] = __builtin_amdgcn_mfma_f32_16x16x32_bf16(af, vr4, acc[fm][4], 0,0,0);
      acc[fm][5] = __builtin_amdgcn_mfma_f32_16x16x32_bf16(af, vr5, acc[fm][5], 0,0,0);
      acc[fm][6] = __builtin_amdgcn_mfma_f32_16x16x32_bf16(af, vr6, acc[fm][6], 0,0,0);
      acc[fm][7] = __builtin_amdgcn_mfma_f32_16x16x32_bf16(af, vr7, acc[fm][7], 0,0,0);
    }
    ka = kna; kc = knc;
    vr0 = vn0; vr1 = vn1; vr2 = vn2; vr3 = vn3;
    vr4 = vn4; vr5 = vn5; vr6 = vn6; vr7 = vn7;
  }

  #pragma unroll
  for (int fm = 0; fm < 4; ++fm){
    #pragma unroll
    for (int r = 0; r < 4; ++r){
      int row = t0 + fm*16 + h*4 + r;
      float inv = 1.f / drow[b*T_ + row];
      #pragma unroll
      for (int fn = 0; fn < 8; ++fn){
        int col = ebase + fn*16 + l15;
        zraw[((size_t)b*T_ + row)*E_ + col] = f2bf(acc[fm][fn][r] * inv);
      }
    }
  }
}

// ---- LN (one wave per row). FINAL=0: bf16 out. FINAL=1: relu -> fp32 out ---
template<int FINAL>
__global__ __launch_bounds__(256) void k_ln(const u16* __restrict__ in,
    const float* __restrict__ g, const float* __restrict__ bt,
    void* __restrict__ outp){
  int row  = blockIdx.x * 4 + (threadIdx.x >> 6);
  int lane = threadIdx.x & 63;
  const u16* r = in + (size_t)row * E_;
  uint4 u0 = *(const uint4*)(r + lane*16);
  uint4 u1 = *(const uint4*)(r + lane*16 + 8);
  u32 uu[8] = {u0.x, u0.y, u0.z, u0.w, u1.x, u1.y, u1.z, u1.w};
  float v[16];
  #pragma unroll
  for (int j = 0; j < 8; ++j){
    v[2*j]   = bf2f(uu[j] & 0xffffu);
    v[2*j+1] = bf2f(uu[j] >> 16);
  }
  float s1 = 0.f, s2 = 0.f;
  #pragma unroll
  for (int j = 0; j < 16; ++j){ s1 += v[j]; s2 += v[j]*v[j]; }
  s1 = wredsum(s1); s2 = wredsum(s2);
  float mean = s1 * (1.f/E_);
  float var  = s2 * (1.f/E_) - mean*mean;
  float rs   = rsqrtf(var + 1e-3f);
  const f4* g4 = (const f4*)g + lane*4;
  const f4* b4 = (const f4*)bt + lane*4;
  float o[16];
  #pragma unroll
  for (int jj = 0; jj < 4; ++jj){
    f4 gg = g4[jj], bb = b4[jj];
    o[4*jj+0] = (v[4*jj+0]-mean)*rs*gg.x + bb.x;
    o[4*jj+1] = (v[4*jj+1]-mean)*rs*gg.y + bb.y;
    o[4*jj+2] = (v[4*jj+2]-mean)*rs*gg.z + bb.z;
    o[4*jj+3] = (v[4*jj+3]-mean)*rs*gg.w + bb.w;
  }
  if (FINAL){
    f4* od = (f4*)((float*)outp + (size_t)row * E_ + lane*16);
    #pragma unroll
    for (int jj = 0; jj < 4; ++jj){
      f4 t;
      t.x = fmaxf(o[4*jj+0], 0.f); t.y = fmaxf(o[4*jj+1], 0.f);
      t.z = fmaxf(o[4*jj+2], 0.f); t.w = fmaxf(o[4*jj+3], 0.f);
      od[jj] = t;
    }
  } else {
    u16* ob = (u16*)outp + (size_t)row * E_ + lane*16;
    u32 pu[8];
    #pragma unroll
    for (int j = 0; j < 8; ++j)
      pu[j] = (u32)f2bf(o[2*j]) | ((u32)f2bf(o[2*j+1]) << 16);
    uint4 w0 = {pu[0], pu[1], pu[2], pu[3]};
    uint4 w1 = {pu[4], pu[5], pu[6], pu[7]};
    *(uint4*)ob       = w0;
    *(uint4*)(ob + 8) = w1;
  }
}

// ---------------------------------------------------------------------------
extern "C" void kernel_launch(void* const* d_in, const int* in_sizes, int n_in,
                              void* d_out, int out_size, void* d_ws, size_t ws_size,
                              hipStream_t stream){
  const float* token = (const float*)d_in[0];
  const float* Wk    = (const float*)d_in[1];
  const float* bk    = (const float*)d_in[2];
  const float* Wq    = (const float*)d_in[3];
  const float* bq    = (const float*)d_in[4];
  const float* Wv    = (const float*)d_in[5];
  const float* bv    = (const float*)d_in[6];
  const float* g1    = (const float*)d_in[7];
  const float* b1    = (const float*)d_in[8];
  const float* g2    = (const float*)d_in[9];
  const float* b2    = (const float*)d_in[10];

  char* ws = (char*)d_ws;
  u16*   wvT   = (u16*)ws;
  float* key   = (float*)(ws + (2u<<20));
  float* query = (float*)(ws + (2u<<20) + (64u<<10));
  float* mrow  = (float*)(ws + (2u<<20) + (128u<<10));
  float* drow  = (float*)(ws + (2u<<20) + (192u<<10));
  float* kstat = (float*)(ws + (2u<<20) + (256u<<10));
  u16* X = (u16*)(ws + (4u<<20));
  u16* V = (u16*)(ws + (36u<<20));
  float* out = (float*)d_out;

  k_prep <<<dim3(BT_/4), 256, 0, stream>>>(token, Wk, bk, Wq, bq, key, query, X);
  k_stats<<<dim3(B_),    256, 0, stream>>>(key, kstat);
  k_denom<<<dim3(BT_/4), 256, 0, stream>>>(key, query, kstat, mrow, drow);
  k_wvT  <<<dim3(E_/32, E_/32), 256, 0, stream>>>(Wv, wvT);
  // value GEMM: A=token_bf16 (X), writes valT directly (V)
  k_gemm<0><<<dim3((BT_/128)*(E_/128)), 256, 0, stream>>>(X, wvT, bv, nullptr, V);
  // PV: reads valT (V), writes zraw (X; token_bf dead)
  k_pv   <<<dim3((T_/64)*(E_/512)*B_), 256, 0, stream>>>(query, key, mrow, drow, V, X);
  // LN1: X -> V (z1; valT dead)
  k_ln<0><<<dim3(BT_/4), 256, 0, stream>>>(X, g1, b1, (void*)V);
  // gemm2 + residual: A=resid=z1 (V), writes y (X)
  k_gemm<1><<<dim3((BT_/128)*(E_/128)), 256, 0, stream>>>(V, wvT, bv, V, X);
  // LN2 + relu: X -> out (fp32)
  k_ln<1><<<dim3(BT_/4), 256, 0, stream>>>(X, g2, b2, (void*)out);
}